// Round 3
// baseline (567.101 us; speedup 1.0000x reference)
//
#include <hip/hip_runtime.h>

#define NN 100000
#define NE 1600000
#define HID 128
#define ODIM 64
#define NBK 196          // ceil(NN/512) buckets of 512 nodes
#define BSHIFT 9
#define BINCAP 12288     // csr records per bucket region (mean ~8192, +45 sigma)
#define P1B 1024         // k_p1 main blocks
#define CVTB 48          // extra k_p1 blocks doing weight cvt
#define P2B 2048         // k_p2 blocks

typedef unsigned int u32;
typedef unsigned short u16;
typedef __bf16 bf16x8 __attribute__((ext_vector_type(8)));
typedef float f32x4 __attribute__((ext_vector_type(4)));
typedef float f32x2 __attribute__((ext_vector_type(2)));

__device__ __forceinline__ float bf_lo(u32 p){ return __uint_as_float(p << 16); }
__device__ __forceinline__ float bf_hi(u32 p){ return __uint_as_float(p & 0xffff0000u); }
__device__ __forceinline__ u16 f2bf(float f){
  u32 u = __float_as_uint(f);
  u += 0x7fffu + ((u >> 16) & 1u);   // RTNE
  return (u16)(u >> 16);
}
__device__ __forceinline__ bf16x8 ld8bf(const u16* p){ return *(const bf16x8*)p; }
__device__ __forceinline__ bf16x8 cvt8(const float* p){
  union { bf16x8 v; u16 s[8]; } r;
#pragma unroll
  for (int i = 0; i < 8; i++) r.s[i] = f2bf(p[i]);
  return r.v;
}
__device__ __forceinline__ float deg2dis(u32 dfx){
  return rsqrtf(1.f + (float)dfx * (1.f / 1048576.f));
}

// -- pass 1: edge means + minmax + per-node histogram (global atomics) ----
//    extra blocks convert weights to bf16.
//    minmax: mm[0]=max(~bits(min)), mm[1]=max(bits(max)), 0-init (m >= 0).
__global__ __launch_bounds__(256) void k_p1(
    const float* __restrict__ eattr, const int* __restrict__ ecol,
    u32* __restrict__ cnt, float* __restrict__ marr, u32* __restrict__ minmax,
    const float* __restrict__ W1, const float* __restrict__ W2,
    const float* __restrict__ Wr, u16* __restrict__ W1b,
    u16* __restrict__ W2b, u16* __restrict__ Wrb){
  int tid = threadIdx.x;
  if (blockIdx.x >= P1B){                      // weight-conversion blocks
    int i = (blockIdx.x - P1B) * 256 + tid;    // 12288 float4 slots
    const float* src; u16* dst; int off;
    if (i < 4096){ src = W1; dst = W1b; off = i; }
    else if (i < 8192){ src = W2; dst = W2b; off = i - 4096; }
    else { src = Wr; dst = Wrb; off = i - 8192; }
    float4 v = ((const float4*)src)[off];
    uint2 o;
    o.x = (u32)f2bf(v.x) | ((u32)f2bf(v.y) << 16);
    o.y = (u32)f2bf(v.z) | ((u32)f2bf(v.w) << 16);
    ((uint2*)dst)[off] = o;
    return;
  }
  __shared__ float smin[4], smax[4];
  int wid = tid >> 6, lane = tid & 63;
  float lmin = __uint_as_float(0x7f800000u), lmax = 0.f;
  for (int e = blockIdx.x * 256 + tid; e < NE; e += P1B * 256){
    float4 a = ((const float4*)eattr)[e];
    float m = 0.25f * (a.x + a.y + a.z + a.w);
    marr[e] = m;
    lmin = fminf(lmin, m); lmax = fmaxf(lmax, m);
    u32 c = (u32)ecol[e];
    if (c < NN) atomicAdd(&cnt[c], 1u);        // fire-and-forget histogram
  }
  for (int off = 32; off; off >>= 1){
    lmin = fminf(lmin, __shfl_xor(lmin, off));
    lmax = fmaxf(lmax, __shfl_xor(lmax, off));
  }
  if (lane == 0){ smin[wid] = lmin; smax[wid] = lmax; }
  __syncthreads();
  if (tid == 0){
    float mn = fminf(fminf(smin[0], smin[1]), fminf(smin[2], smin[3]));
    float mx = fmaxf(fmaxf(smax[0], smax[1]), fmaxf(smax[2], smax[3]));
    atomicMax(&minmax[0], ~__float_as_uint(mn));  // nonneg: bit order == value order
    atomicMax(&minmax[1], __float_as_uint(mx));
  }
}

// -- per-bucket exclusive scan: counts -> meta (rs|cnt<<22) + cur ---------
__global__ __launch_bounds__(512) void k_scan(
    const u32* __restrict__ cnt, u32* __restrict__ meta, u32* __restrict__ cur){
  __shared__ u32 sc[512];
  int b = blockIdx.x, tid = threadIdx.x;
  int node = (b << BSHIFT) + tid;
  u32 v = (node < NN) ? cnt[node] : 0u;
  sc[tid] = v; __syncthreads();
  for (int s = 1; s < 512; s <<= 1){
    u32 t = (tid >= s) ? sc[tid - s] : 0u;
    __syncthreads();
    sc[tid] += t;
    __syncthreads();
  }
  u32 rs = (u32)(b * BINCAP) + (sc[tid] - v);  // bucket-padded absolute index
  if (node < NN){
    meta[node] = rs | (v << 22);               // rs<2.41M fits 22b; cnt<1024
    cur[node] = rs;
  }
}

// -- pass 2: weights + counting-sort scatter into csr + weighted degree ---
__global__ __launch_bounds__(256) void k_p2(
    const float* __restrict__ marr, const int* __restrict__ erow,
    const int* __restrict__ ecol, const u32* __restrict__ minmax,
    u32* __restrict__ cur, u32* __restrict__ csr, u32* __restrict__ degfx){
  float mn  = __uint_as_float(~minmax[0]);
  float mx  = __uint_as_float(minmax[1]);
  float rng = mx - mn;
  bool flat = !(rng > 1e-8f);
  float inv = 1.f / (rng + 1e-8f);
  for (int e = blockIdx.x * 256 + threadIdx.x; e < NE; e += P2B * 256){
    float m = marr[e];
    u32 c = (u32)ecol[e];
    u32 s = (u32)erow[e]; if (s >= NN) s = 0;  // never triggers (randint<NN)
    if (c >= NN) continue;
    float w = flat ? 1.f : fmaxf(1.f - (m - mn) * inv, 0.f);
    u32 pos = atomicAdd(&cur[c], 1u);
    csr[pos] = s | ((u32)(w * 32767.f + 0.5f) << 17);   // src:17 | w:15
    atomicAdd(&degfx[c], (u32)(w * 1048576.f + 0.5f));  // 2^20 fixed point
  }
}

// -- bf16 MFMA GEMM: G[M,128] = dis[m]*(A[M,128] @ Bt[128,128]^T) ---------
// One block = 32 rows x ALL 128 cols (wave: 2 m-tiles x 2 n-tiles).
template <bool A_F32>
__global__ __launch_bounds__(256) void k_gemm128(
    const void* __restrict__ Av, const u16* __restrict__ Bt,
    const u32* __restrict__ degfx, u16* __restrict__ G){
  int wave = threadIdx.x >> 6, lane = threadIdx.x & 63;
  int m0 = blockIdx.x * 32;
  int m = lane & 15, q = lane >> 4;
  const float* a0f = (const float*)Av + (size_t)(m0 + m) * HID;
  const float* a1f = a0f + (size_t)16 * HID;
  const u16*   a0b = (const u16*)Av   + (size_t)(m0 + m) * HID;
  const u16*   a1b = a0b + (size_t)16 * HID;
  const u16* brow0 = Bt + (size_t)(wave * 16 + m) * HID;
  const u16* brow1 = brow0 + (size_t)64 * HID;
  f32x4 acc00 = {0.f,0.f,0.f,0.f}, acc01 = {0.f,0.f,0.f,0.f};
  f32x4 acc10 = {0.f,0.f,0.f,0.f}, acc11 = {0.f,0.f,0.f,0.f};
#pragma unroll
  for (int kb = 0; kb < HID; kb += 32){
    bf16x8 af0 = A_F32 ? cvt8(a0f + kb + q * 8) : ld8bf(a0b + kb + q * 8);
    bf16x8 af1 = A_F32 ? cvt8(a1f + kb + q * 8) : ld8bf(a1b + kb + q * 8);
    bf16x8 bf0 = ld8bf(brow0 + kb + q * 8);
    bf16x8 bf1 = ld8bf(brow1 + kb + q * 8);
    acc00 = __builtin_amdgcn_mfma_f32_16x16x32_bf16(af0, bf0, acc00, 0, 0, 0);
    acc01 = __builtin_amdgcn_mfma_f32_16x16x32_bf16(af0, bf1, acc01, 0, 0, 0);
    acc10 = __builtin_amdgcn_mfma_f32_16x16x32_bf16(af1, bf0, acc10, 0, 0, 0);
    acc11 = __builtin_amdgcn_mfma_f32_16x16x32_bf16(af1, bf1, acc11, 0, 0, 0);
  }
  u16* crow0 = G + (size_t)(m0 + q * 4) * HID + wave * 16 + m;
  u16* crow1 = crow0 + (size_t)16 * HID;
#pragma unroll
  for (int r = 0; r < 4; r++){
    float d0 = deg2dis(degfx[m0 + q * 4 + r]);
    float d1 = deg2dis(degfx[m0 + 16 + q * 4 + r]);
    crow0[(size_t)r * HID]      = f2bf(acc00[r] * d0);
    crow0[(size_t)r * HID + 64] = f2bf(acc01[r] * d0);
    crow1[(size_t)r * HID]      = f2bf(acc10[r] * d1);
    crow1[(size_t)r * HID + 64] = f2bf(acc11[r] * d1);
  }
}

// ------- aggregation: wave/node, scalar csr records, integer weights -----
// h_i = relu( dis_i * (sum_e w_e * g[src_e] + g_i) + b )
// Per-node state is wave-scalar (readfirstlane) -> meta/degfx/csr go through
// the scalar path; gathers keep saddr form (SGPR base, lane*4 offset).
// Weights accumulate as integers (w_int in [0,32767]); 1/32767 folded into
// dis at the epilogue. Full 16-edge chunks have no per-edge conditionals;
// masked 8-chunks clamp pad edges to src=0 / w=0 (row 0 stays cache-hot).
__global__ __launch_bounds__(256) void k_aggregate(
    const u32* __restrict__ meta, const u32* __restrict__ csr,
    const u32* __restrict__ degfx, const u16* __restrict__ g,
    const float* __restrict__ bias, u16* __restrict__ hout){
  int node = __builtin_amdgcn_readfirstlane(
      (int)(blockIdx.x * 4 + (threadIdx.x >> 6)));
  int lane = threadIdx.x & 63;
  const u32* gp = (const u32*)g;
  u32 sv = gp[((size_t)node << 6) + lane];     // self row, issued early
  u32 mw = meta[node];                          // uniform -> scalar load
  float di = deg2dis(degfx[node]);              // uniform -> scalar load
  u32 s = mw & 0x3FFFFFu;
  int c = (int)(mw >> 22);
  const u32* cp = csr + s;
  f32x2 acc = {0.f, 0.f};
  int j = 0;
  // full 16-edge chunks: 16 gathers in flight, no conditionals
  for (; j + 16 <= c; j += 16){
    u32 p[16];
#pragma unroll
    for (int t = 0; t < 16; t++)
      p[t] = __builtin_amdgcn_readfirstlane(cp[j + t]);
    u32 pv[16];
#pragma unroll
    for (int t = 0; t < 16; t++)
      pv[t] = gp[(size_t)(p[t] & 0x1FFFFu) * 64u + lane];
#pragma unroll
    for (int t = 0; t < 16; t++){
      float wf = (float)(p[t] >> 17);
      f32x2 val = {bf_lo(pv[t]), bf_hi(pv[t])};
      f32x2 w2 = {wf, wf};
      acc += w2 * val;
    }
  }
  // masked 8-edge chunks for the tail (src->0, w->0 beyond c)
  for (; j < c; j += 8){
    u32 p[8];
#pragma unroll
    for (int t = 0; t < 8; t++)
      p[t] = __builtin_amdgcn_readfirstlane(cp[j + t]);  // bucket slack: safe
    u32 st[8]; u32 wi[8];
#pragma unroll
    for (int t = 0; t < 8; t++){
      bool ok = (j + t) < c;                   // wave-uniform condition
      st[t] = ok ? (p[t] & 0x1FFFFu) : 0u;
      wi[t] = ok ? (p[t] >> 17) : 0u;
    }
    u32 pv[8];
#pragma unroll
    for (int t = 0; t < 8; t++)
      pv[t] = gp[(size_t)st[t] * 64u + lane];
#pragma unroll
    for (int t = 0; t < 8; t++){
      float wf = (float)wi[t];
      f32x2 val = {bf_lo(pv[t]), bf_hi(pv[t])};
      f32x2 w2 = {wf, wf};
      acc += w2 * val;
    }
  }
  float2 bv = ((const float2*)bias)[lane];
  f32x2 selfv = {bf_lo(sv), bf_hi(sv)};
  float d2 = di * (1.f / 32767.f);             // fold fixed-point scale
  float o0 = fmaxf(acc.x * d2 + (selfv.x * di + bv.x), 0.f);
  float o1 = fmaxf(acc.y * d2 + (selfv.y * di + bv.y), 0.f);
  ((u32*)hout)[((size_t)node << 6) + lane] = (u32)f2bf(o0) | ((u32)f2bf(o1) << 16);
}

// -- readout: out[M,64] = [h1|h2] @ Wr^T + br (f32 out), 32 rows/block ----
__global__ __launch_bounds__(256) void k_readout(
    const u16* __restrict__ h1, const u16* __restrict__ h2,
    const u16* __restrict__ Wrb, const float* __restrict__ br, float* __restrict__ out){
  int wave = threadIdx.x >> 6, lane = threadIdx.x & 63;
  int m0 = blockIdx.x * 32;
  int n0 = wave * 16;
  int m = lane & 15, q = lane >> 4;
  const u16* a10 = h1 + (size_t)(m0 + m) * HID;
  const u16* a11 = a10 + (size_t)16 * HID;
  const u16* a20 = h2 + (size_t)(m0 + m) * HID;
  const u16* a21 = a20 + (size_t)16 * HID;
  const u16* b  = Wrb + (size_t)(n0 + m) * (2 * HID);
  f32x4 acc0 = {0.f,0.f,0.f,0.f}, acc1 = {0.f,0.f,0.f,0.f};
#pragma unroll
  for (int kb = 0; kb < HID; kb += 32){
    bf16x8 bf = ld8bf(b + kb + q * 8);
    acc0 = __builtin_amdgcn_mfma_f32_16x16x32_bf16(ld8bf(a10 + kb + q * 8), bf, acc0, 0, 0, 0);
    acc1 = __builtin_amdgcn_mfma_f32_16x16x32_bf16(ld8bf(a11 + kb + q * 8), bf, acc1, 0, 0, 0);
  }
#pragma unroll
  for (int kb = 0; kb < HID; kb += 32){
    bf16x8 bf = ld8bf(b + HID + kb + q * 8);
    acc0 = __builtin_amdgcn_mfma_f32_16x16x32_bf16(ld8bf(a20 + kb + q * 8), bf, acc0, 0, 0, 0);
    acc1 = __builtin_amdgcn_mfma_f32_16x16x32_bf16(ld8bf(a21 + kb + q * 8), bf, acc1, 0, 0, 0);
  }
  float bias = br[n0 + m];
  float* crow0 = out + (size_t)(m0 + q * 4) * ODIM + n0 + m;
  float* crow1 = crow0 + (size_t)16 * ODIM;
#pragma unroll
  for (int r = 0; r < 4; r++){
    crow0[(size_t)r * ODIM] = acc0[r] + bias;
    crow1[(size_t)r * ODIM] = acc1[r] + bias;
  }
}

// ---------------- launch --------------------------------------------------
extern "C" void kernel_launch(void* const* d_in, const int* in_sizes, int n_in,
                              void* d_out, int out_size, void* d_ws, size_t ws_size,
                              hipStream_t stream){
  const float* x     = (const float*)d_in[0];
  const int*   eidx  = (const int*)d_in[1];
  const float* eattr = (const float*)d_in[2];
  const float* W1    = (const float*)d_in[3];
  const float* b1    = (const float*)d_in[4];
  const float* W2    = (const float*)d_in[5];
  const float* b2    = (const float*)d_in[6];
  const float* Wr    = (const float*)d_in[7];
  const float* br    = (const float*)d_in[8];
  const int* erow  = eidx;        // edge_index[0]
  const int* ecol  = eidx + NE;   // edge_index[1]

  char* w = (char*)d_ws;
  auto carve = [&](size_t bytes) -> void* {
    void* p = (void*)w;
    w += (bytes + 255) & ~(size_t)255;
    return p;
  };
  u32* csr       = (u32*)carve((size_t)NBK * BINCAP * 4);  // bucket-padded, 4B recs
  u32* cnt       = (u32*)carve((size_t)NN * 4);   // cnt,degfx,minmax contiguous
  u32* degfx     = (u32*)carve((size_t)NN * 4);   // (one memset covers all 3)
  u32* minmax    = (u32*)carve(256);
  u32* cur       = (u32*)carve((size_t)NN * 4);
  u32* meta      = (u32*)carve((size_t)NN * 4);   // rs|cnt<<22 packed
  u16* W1b       = (u16*)carve((size_t)HID * HID * 2);
  u16* W2b       = (u16*)carve((size_t)HID * HID * 2);
  u16* Wrb       = (u16*)carve((size_t)ODIM * 2 * HID * 2);
  u16* g         = (u16*)carve((size_t)NN * HID * 2);
  u16* h1        = (u16*)carve((size_t)NN * HID * 2);
  u16* h2        = (u16*)carve((size_t)NN * HID * 2);
  float* marr    = (float*)g;    // alias: marr dead before k_gemm128 writes g

  size_t zspan = (size_t)((char*)minmax + 256 - (char*)cnt);
  hipMemsetAsync(cnt, 0, zspan, stream);          // cnt + degfx + minmax
  k_p1<<<P1B + CVTB, 256, 0, stream>>>(eattr, ecol, cnt, marr, minmax,
                                       W1, W2, Wr, W1b, W2b, Wrb);
  k_scan<<<NBK, 512, 0, stream>>>(cnt, meta, cur);
  k_p2<<<P2B, 256, 0, stream>>>(marr, erow, ecol, minmax, cur, csr, degfx);

  // layer 1: g = dis * (x @ W1^T)  (f32 A converted inline)
  k_gemm128<true><<<NN / 32, 256, 0, stream>>>(x, W1b, degfx, g);
  k_aggregate<<<NN / 4, 256, 0, stream>>>(meta, csr, degfx, g, b1, h1);
  // layer 2
  k_gemm128<false><<<NN / 32, 256, 0, stream>>>(h1, W2b, degfx, g);
  k_aggregate<<<NN / 4, 256, 0, stream>>>(meta, csr, degfx, g, b2, h2);
  // readout
  k_readout<<<NN / 32, 256, 0, stream>>>(h1, h2, Wrb, br, (float*)d_out);
}

// Round 4
// 428.987 us; speedup vs baseline: 1.3220x; 1.3220x over previous
//
#include <hip/hip_runtime.h>

#define NN 100000
#define NE 1600000
#define HID 128
#define ODIM 64
#define NBK 196          // ceil(NN/512) buckets of 512 nodes
#define BSHIFT 9
#define BGRID 512        // k_bin main blocks
#define CVTB 48          // extra k_bin blocks doing weight cvt
#define CHUNK 3125       // NE / BGRID (exact)
#define BITER 13         // ceil(CHUNK/256)
#define BINCAP 12288     // records per bucket region (mean ~8192, +45 sigma)
#define SMAX 4504        // LDS staging records >= 3125 + 196*7 = 4497
#define LMAX 568         // line map entries >= SMAX/8

typedef unsigned int u32;
typedef unsigned short u16;
typedef __bf16 bf16x8 __attribute__((ext_vector_type(8)));
typedef float f32x4 __attribute__((ext_vector_type(4)));
typedef float f32x2 __attribute__((ext_vector_type(2)));

__device__ __forceinline__ float bf_lo(u32 p){ return __uint_as_float(p << 16); }
__device__ __forceinline__ float bf_hi(u32 p){ return __uint_as_float(p & 0xffff0000u); }
__device__ __forceinline__ u16 f2bf(float f){
  u32 u = __float_as_uint(f);
  u += 0x7fffu + ((u >> 16) & 1u);   // RTNE
  return (u16)(u >> 16);
}
__device__ __forceinline__ bf16x8 ld8bf(const u16* p){ return *(const bf16x8*)p; }
__device__ __forceinline__ bf16x8 cvt8(const float* p){
  union { bf16x8 v; u16 s[8]; } r;
#pragma unroll
  for (int i = 0; i < 8; i++) r.s[i] = f2bf(p[i]);
  return r.v;
}

// -- fused edge pass + bin + global histogram; extra blocks cvt weights.
//    Per-wave privatized bucket counters (4x less LDS-atomic contention).
//    Global cnt histogram is fire-and-forget (cheap, proven R3).
//    minmax: mm[0]=max(~bits(min)), mm[1]=max(bits(max)), 0-init.
__global__ __launch_bounds__(256) void k_bin(
    const float* __restrict__ eattr, const int* __restrict__ erow,
    const int* __restrict__ ecol, u32* __restrict__ bcur,
    uint2* __restrict__ bin, u32* __restrict__ minmax, u32* __restrict__ cnt,
    const float* __restrict__ W1, const float* __restrict__ W2,
    const float* __restrict__ Wr, u16* __restrict__ W1b,
    u16* __restrict__ W2b, u16* __restrict__ Wrb){
  int tid = threadIdx.x;
  if (blockIdx.x >= BGRID){                    // weight-conversion blocks
    int i = (blockIdx.x - BGRID) * 256 + tid;  // 12288 float4 slots
    const float* src; u16* dst; int off;
    if (i < 4096){ src = W1; dst = W1b; off = i; }
    else if (i < 8192){ src = W2; dst = W2b; off = i - 4096; }
    else { src = Wr; dst = Wrb; off = i - 8192; }
    float4 v = ((const float4*)src)[off];
    uint2 o;
    o.x = (u32)f2bf(v.x) | ((u32)f2bf(v.y) << 16);
    o.y = (u32)f2bf(v.z) | ((u32)f2bf(v.w) << 16);
    ((uint2*)dst)[off] = o;
    return;
  }
  __shared__ u32 lcnt4[4 * NBK], wof4[4 * NBK];
  __shared__ u32 lofs[NBK], gb[NBK];
  __shared__ u32 scn[256];
  __shared__ u16 lmap[LMAX];
  __shared__ uint2 stage[SMAX];
  __shared__ u32 Tt;
  __shared__ float smin[4], smax[4];
  for (int t = tid; t < 4 * NBK; t += 256) lcnt4[t] = 0;
  __syncthreads();
  int base = blockIdx.x * CHUNK;
  int wid = tid >> 6, lane = tid & 63;
  float lmin = __uint_as_float(0x7f800000u), lmax = 0.f;
  u32 pk[BITER]; float mv[BITER]; u32 sv[BITER];
#pragma unroll
  for (int it = 0; it < BITER; it++){
    int idx = it * 256 + tid;
    u32 p = 0xFFFFFFFFu; float m = 0.f; u32 s = 0;
    if (idx < CHUNK){
      int e = base + idx;
      float4 a = ((const float4*)eattr)[e];
      m = 0.25f * (a.x + a.y + a.z + a.w);
      lmin = fminf(lmin, m); lmax = fmaxf(lmax, m);
      int c = ecol[e];
      s = (u32)erow[e]; if (s >= NN) s = 0;    // never triggers (randint<NN)
      if ((u32)c < NN){
        u32 b = (u32)c >> BSHIFT;
        u32 r = atomicAdd(&lcnt4[wid * NBK + b], 1u);   // r <= 13*64 < 4096
        p = (b << 21) | (((u32)c & 511u) << 12) | r;
        atomicAdd(&cnt[c], 1u);                // fire-and-forget histogram
      }
    }
    pk[it] = p; mv[it] = m; sv[it] = s;
  }
  __syncthreads();
  // combine per-wave counts; padded scan; global region alloc; line map
  u32 na = 0, n = 0;
  if (tid < NBK){
    u32 n0 = lcnt4[tid], n1 = lcnt4[NBK + tid];
    u32 n2 = lcnt4[2 * NBK + tid], n3 = lcnt4[3 * NBK + tid];
    n = n0 + n1 + n2 + n3;
    na = (n + 7u) & ~7u;
    wof4[tid] = 0; wof4[NBK + tid] = n0;
    wof4[2 * NBK + tid] = n0 + n1; wof4[3 * NBK + tid] = n0 + n1 + n2;
  }
  scn[tid] = na; __syncthreads();
  for (int s = 1; s < 256; s <<= 1){
    u32 t = (tid >= s) ? scn[tid - s] : 0;
    __syncthreads();
    scn[tid] += t;
    __syncthreads();
  }
  u32 ex = scn[tid] - na;
  if (tid < NBK){
    lofs[tid] = ex;
    u32 g = 0x80000000u;
    if (na){
      u32 gl = atomicAdd(&bcur[tid], na);      // bcur 0-init by memset
      if (gl + na <= BINCAP) g = (u32)tid * BINCAP + gl;
    }
    gb[tid] = g;
    for (u32 l = ex >> 3; l < (ex + na) >> 3; l++) lmap[l] = (u16)tid;
    uint2 sent; sent.x = 0xFFFFFFFFu; sent.y = 0u;
    for (u32 k = n; k < na; k++) stage[ex + k] = sent;   // pad slots only
  }
  if (tid == 255) Tt = scn[255];
  __syncthreads();
  // place records bucket-major in LDS
#pragma unroll
  for (int it = 0; it < BITER; it++){
    u32 p = pk[it];
    if (p == 0xFFFFFFFFu) continue;
    u32 b = p >> 21;
    uint2 rec; rec.x = sv[it] | (((p >> 12) & 511u) << 17); rec.y = __float_as_uint(mv[it]);
    stage[lofs[b] + wof4[wid * NBK + b] + (p & 4095u)] = rec;
  }
  __syncthreads();
  // stream out: consecutive threads -> consecutive slots in full-line runs
  u32 T = Tt;
  for (u32 i = tid; i < T; i += 256){
    u32 b = lmap[i >> 3];
    u32 g = gb[b];
    if (g != 0x80000000u) bin[g + (i - lofs[b])] = stage[i];
  }
  // min/max reduce + global update (0-init compatible encoding)
  for (int off = 32; off; off >>= 1){
    lmin = fminf(lmin, __shfl_xor(lmin, off));
    lmax = fmaxf(lmax, __shfl_xor(lmax, off));
  }
  if (lane == 0){ smin[wid] = lmin; smax[wid] = lmax; }
  __syncthreads();
  if (tid == 0){
    float mn = fminf(fminf(smin[0], smin[1]), fminf(smin[2], smin[3]));
    float mx = fmaxf(fmaxf(smax[0], smax[1]), fmaxf(smax[2], smax[3]));
    atomicMax(&minmax[0], ~__float_as_uint(mn));  // nonneg: bit order == value order
    atomicMax(&minmax[1], __float_as_uint(mx));
  }
}

// -- per-bucket offset scan (shfl-based, 1 barrier): cnt -> meta + cur ----
__global__ __launch_bounds__(512) void k_scan(
    const u32* __restrict__ cnt, u32* __restrict__ meta, u32* __restrict__ cur){
  __shared__ u32 wtot[8];
  int b = blockIdx.x, tid = threadIdx.x;
  int wid = tid >> 6, lane = tid & 63;
  int node = (b << BSHIFT) + tid;
  u32 v = (node < NN) ? cnt[node] : 0u;
  u32 incl = v;
  for (int off = 1; off < 64; off <<= 1){
    u32 t = (u32)__shfl_up((int)incl, off);
    if (lane >= off) incl += t;
  }
  if (lane == 63) wtot[wid] = incl;
  __syncthreads();
  u32 pre = 0;
#pragma unroll
  for (int k = 0; k < 8; k++) pre += (k < wid) ? wtot[k] : 0u;
  u32 rs = (u32)(b * BINCAP) + pre + incl - v;   // exclusive, bucket-padded abs
  if (node < NN){
    meta[node] = rs | (v << 22);               // rs<2.41M fits 22b; cnt<=1023
    cur[node] = rs;
  }
}

// -- scatter: bin records -> final csr positions via LDS returning atomics
//    4 KB LDS (vs k_sort's 98 KB staging); single pass over records.
__global__ __launch_bounds__(1024) void k_scatter(
    const u32* __restrict__ bcur, const uint2* __restrict__ bin,
    const u32* __restrict__ minmax, const u32* __restrict__ cur,
    u32* __restrict__ csr, float* __restrict__ dis){
  __shared__ u32 curL[512], degL[512];
  int b = blockIdx.x, tid = threadIdx.x;
  int bb = b * BINCAP;
  int nrec = (int)min(bcur[b], (u32)BINCAP);
  if (tid < 512){
    int node = (b << BSHIFT) + tid;
    curL[tid] = (node < NN) ? cur[node] : 0u;
    degL[tid] = 0u;
  }
  __syncthreads();
  float mn  = __uint_as_float(~minmax[0]);
  float mx  = __uint_as_float(minmax[1]);
  float rng = mx - mn;
  bool flat = !(rng > 1e-8f);
  float inv = 1.f / (rng + 1e-8f);
  for (int i = tid; i < nrec; i += 1024){
    uint2 r = bin[bb + i];
    if (r.x == 0xFFFFFFFFu) continue;          // pad sentinel
    u32 d = (r.x >> 17) & 511u;
    float w = flat ? 1.f : fmaxf(1.f - (__uint_as_float(r.y) - mn) * inv, 0.f);
    u32 pos = atomicAdd(&curL[d], 1u);         // LDS returning atomic (fast)
    csr[pos] = (r.x & 0x1FFFFu) | ((u32)(w * 32767.f + 0.5f) << 17);
    atomicAdd(&degL[d], (u32)(w * 1048576.f + 0.5f));  // 2^20 fixed point
  }
  __syncthreads();
  if (tid < 512){
    int node = (b << BSHIFT) + tid;
    if (node < NN) dis[node] = rsqrtf(1.f + (float)degL[tid] * (1.f / 1048576.f));
  }
}

// -- bf16 MFMA GEMM: G[M,128] = dis[m]*(A[M,128] @ Bt[128,128]^T) ---------
// One block = 32 rows x ALL 128 cols (wave: 2 m-tiles x 2 n-tiles).
template <bool A_F32>
__global__ __launch_bounds__(256) void k_gemm128(
    const void* __restrict__ Av, const u16* __restrict__ Bt,
    const float* __restrict__ dis, u16* __restrict__ G){
  int wave = threadIdx.x >> 6, lane = threadIdx.x & 63;
  int m0 = blockIdx.x * 32;
  int m = lane & 15, q = lane >> 4;
  const float* a0f = (const float*)Av + (size_t)(m0 + m) * HID;
  const float* a1f = a0f + (size_t)16 * HID;
  const u16*   a0b = (const u16*)Av   + (size_t)(m0 + m) * HID;
  const u16*   a1b = a0b + (size_t)16 * HID;
  const u16* brow0 = Bt + (size_t)(wave * 16 + m) * HID;
  const u16* brow1 = brow0 + (size_t)64 * HID;
  f32x4 acc00 = {0.f,0.f,0.f,0.f}, acc01 = {0.f,0.f,0.f,0.f};
  f32x4 acc10 = {0.f,0.f,0.f,0.f}, acc11 = {0.f,0.f,0.f,0.f};
#pragma unroll
  for (int kb = 0; kb < HID; kb += 32){
    bf16x8 af0 = A_F32 ? cvt8(a0f + kb + q * 8) : ld8bf(a0b + kb + q * 8);
    bf16x8 af1 = A_F32 ? cvt8(a1f + kb + q * 8) : ld8bf(a1b + kb + q * 8);
    bf16x8 bf0 = ld8bf(brow0 + kb + q * 8);
    bf16x8 bf1 = ld8bf(brow1 + kb + q * 8);
    acc00 = __builtin_amdgcn_mfma_f32_16x16x32_bf16(af0, bf0, acc00, 0, 0, 0);
    acc01 = __builtin_amdgcn_mfma_f32_16x16x32_bf16(af0, bf1, acc01, 0, 0, 0);
    acc10 = __builtin_amdgcn_mfma_f32_16x16x32_bf16(af1, bf0, acc10, 0, 0, 0);
    acc11 = __builtin_amdgcn_mfma_f32_16x16x32_bf16(af1, bf1, acc11, 0, 0, 0);
  }
  u16* crow0 = G + (size_t)(m0 + q * 4) * HID + wave * 16 + m;
  u16* crow1 = crow0 + (size_t)16 * HID;
#pragma unroll
  for (int r = 0; r < 4; r++){
    float d0 = dis[m0 + q * 4 + r];
    float d1 = dis[m0 + 16 + q * 4 + r];
    crow0[(size_t)r * HID]      = f2bf(acc00[r] * d0);
    crow0[(size_t)r * HID + 64] = f2bf(acc01[r] * d0);
    crow1[(size_t)r * HID]      = f2bf(acc10[r] * d1);
    crow1[(size_t)r * HID + 64] = f2bf(acc11[r] * d1);
  }
}

// ------- aggregation: wave/node, scalar csr records, integer weights -----
// h_i = relu( dis_i * (sum_e w_e * g[src_e] + g_i) + b )
__global__ __launch_bounds__(256) void k_aggregate(
    const u32* __restrict__ meta, const u32* __restrict__ csr,
    const float* __restrict__ dis, const u16* __restrict__ g,
    const float* __restrict__ bias, u16* __restrict__ hout){
  int node = __builtin_amdgcn_readfirstlane(
      (int)(blockIdx.x * 4 + (threadIdx.x >> 6)));
  int lane = threadIdx.x & 63;
  const u32* gp = (const u32*)g;
  u32 sv = gp[((size_t)node << 6) + lane];     // self row, issued early
  u32 mw = meta[node];                          // uniform -> scalar load
  float di = dis[node];                         // uniform -> scalar load
  u32 s = mw & 0x3FFFFFu;
  int c = (int)(mw >> 22);
  const u32* cp = csr + s;
  f32x2 acc = {0.f, 0.f};
  int j = 0;
  // full 16-edge chunks: 16 gathers in flight, no conditionals
  for (; j + 16 <= c; j += 16){
    u32 p[16];
#pragma unroll
    for (int t = 0; t < 16; t++)
      p[t] = __builtin_amdgcn_readfirstlane(cp[j + t]);
    u32 pv[16];
#pragma unroll
    for (int t = 0; t < 16; t++)
      pv[t] = gp[(size_t)(p[t] & 0x1FFFFu) * 64u + lane];
#pragma unroll
    for (int t = 0; t < 16; t++){
      float wf = (float)(p[t] >> 17);
      f32x2 val = {bf_lo(pv[t]), bf_hi(pv[t])};
      f32x2 w2 = {wf, wf};
      acc += w2 * val;
    }
  }
  // masked 8-edge chunks for the tail (src->0, w->0 beyond c)
  for (; j < c; j += 8){
    u32 p[8];
#pragma unroll
    for (int t = 0; t < 8; t++)
      p[t] = __builtin_amdgcn_readfirstlane(cp[j + t]);  // bucket slack: safe
    u32 st[8]; u32 wi[8];
#pragma unroll
    for (int t = 0; t < 8; t++){
      bool ok = (j + t) < c;                   // wave-uniform condition
      st[t] = ok ? (p[t] & 0x1FFFFu) : 0u;
      wi[t] = ok ? (p[t] >> 17) : 0u;
    }
    u32 pv[8];
#pragma unroll
    for (int t = 0; t < 8; t++)
      pv[t] = gp[(size_t)st[t] * 64u + lane];
#pragma unroll
    for (int t = 0; t < 8; t++){
      float wf = (float)wi[t];
      f32x2 val = {bf_lo(pv[t]), bf_hi(pv[t])};
      f32x2 w2 = {wf, wf};
      acc += w2 * val;
    }
  }
  float2 bv = ((const float2*)bias)[lane];
  f32x2 selfv = {bf_lo(sv), bf_hi(sv)};
  float d2 = di * (1.f / 32767.f);             // fold fixed-point scale
  float o0 = fmaxf(acc.x * d2 + (selfv.x * di + bv.x), 0.f);
  float o1 = fmaxf(acc.y * d2 + (selfv.y * di + bv.y), 0.f);
  ((u32*)hout)[((size_t)node << 6) + lane] = (u32)f2bf(o0) | ((u32)f2bf(o1) << 16);
}

// -- readout: out[M,64] = [h1|h2] @ Wr^T + br (f32 out), 32 rows/block ----
__global__ __launch_bounds__(256) void k_readout(
    const u16* __restrict__ h1, const u16* __restrict__ h2,
    const u16* __restrict__ Wrb, const float* __restrict__ br, float* __restrict__ out){
  int wave = threadIdx.x >> 6, lane = threadIdx.x & 63;
  int m0 = blockIdx.x * 32;
  int n0 = wave * 16;
  int m = lane & 15, q = lane >> 4;
  const u16* a10 = h1 + (size_t)(m0 + m) * HID;
  const u16* a11 = a10 + (size_t)16 * HID;
  const u16* a20 = h2 + (size_t)(m0 + m) * HID;
  const u16* a21 = a20 + (size_t)16 * HID;
  const u16* b  = Wrb + (size_t)(n0 + m) * (2 * HID);
  f32x4 acc0 = {0.f,0.f,0.f,0.f}, acc1 = {0.f,0.f,0.f,0.f};
#pragma unroll
  for (int kb = 0; kb < HID; kb += 32){
    bf16x8 bf = ld8bf(b + kb + q * 8);
    acc0 = __builtin_amdgcn_mfma_f32_16x16x32_bf16(ld8bf(a10 + kb + q * 8), bf, acc0, 0, 0, 0);
    acc1 = __builtin_amdgcn_mfma_f32_16x16x32_bf16(ld8bf(a11 + kb + q * 8), bf, acc1, 0, 0, 0);
  }
#pragma unroll
  for (int kb = 0; kb < HID; kb += 32){
    bf16x8 bf = ld8bf(b + HID + kb + q * 8);
    acc0 = __builtin_amdgcn_mfma_f32_16x16x32_bf16(ld8bf(a20 + kb + q * 8), bf, acc0, 0, 0, 0);
    acc1 = __builtin_amdgcn_mfma_f32_16x16x32_bf16(ld8bf(a21 + kb + q * 8), bf, acc1, 0, 0, 0);
  }
  float bias = br[n0 + m];
  float* crow0 = out + (size_t)(m0 + q * 4) * ODIM + n0 + m;
  float* crow1 = crow0 + (size_t)16 * ODIM;
#pragma unroll
  for (int r = 0; r < 4; r++){
    crow0[(size_t)r * ODIM] = acc0[r] + bias;
    crow1[(size_t)r * ODIM] = acc1[r] + bias;
  }
}

// ---------------- launch --------------------------------------------------
extern "C" void kernel_launch(void* const* d_in, const int* in_sizes, int n_in,
                              void* d_out, int out_size, void* d_ws, size_t ws_size,
                              hipStream_t stream){
  const float* x     = (const float*)d_in[0];
  const int*   eidx  = (const int*)d_in[1];
  const float* eattr = (const float*)d_in[2];
  const float* W1    = (const float*)d_in[3];
  const float* b1    = (const float*)d_in[4];
  const float* W2    = (const float*)d_in[5];
  const float* b2    = (const float*)d_in[6];
  const float* Wr    = (const float*)d_in[7];
  const float* br    = (const float*)d_in[8];
  const int* erow  = eidx;        // edge_index[0]
  const int* ecol  = eidx + NE;   // edge_index[1]

  char* w = (char*)d_ws;
  auto carve = [&](size_t bytes) -> void* {
    void* p = (void*)w;
    w += (bytes + 255) & ~(size_t)255;
    return p;
  };
  u32* csr       = (u32*)carve((size_t)NBK * BINCAP * 4);  // bucket-padded, 4B recs
  u32* bcur      = (u32*)carve(256 * 4);          // bcur,minmax,cnt contiguous
  u32* minmax    = (u32*)carve(256);              // (one memset covers all 3)
  u32* cnt       = (u32*)carve((size_t)NN * 4);
  u32* cur       = (u32*)carve((size_t)NN * 4);
  u32* meta      = (u32*)carve((size_t)NN * 4);   // rs|cnt<<22 packed
  float* dis     = (float*)carve((size_t)NN * 4);
  u16* W1b       = (u16*)carve((size_t)HID * HID * 2);
  u16* W2b       = (u16*)carve((size_t)HID * HID * 2);
  u16* Wrb       = (u16*)carve((size_t)ODIM * 2 * HID * 2);
  u16* g         = (u16*)carve((size_t)NN * HID * 2);
  u16* h1        = (u16*)carve((size_t)NN * HID * 2);
  u16* h2        = (u16*)carve((size_t)NN * HID * 2);
  uint2* bin     = (uint2*)h2;   // alias: bin dead after k_scatter; h2 written layer 2

  size_t zspan = (size_t)((char*)cnt + (size_t)NN * 4 - (char*)bcur);
  hipMemsetAsync(bcur, 0, zspan, stream);         // bcur + minmax + cnt
  k_bin<<<BGRID + CVTB, 256, 0, stream>>>(eattr, erow, ecol, bcur, bin, minmax,
                                          cnt, W1, W2, Wr, W1b, W2b, Wrb);
  k_scan<<<NBK, 512, 0, stream>>>(cnt, meta, cur);
  k_scatter<<<NBK, 1024, 0, stream>>>(bcur, bin, minmax, cur, csr, dis);

  // layer 1: g = dis * (x @ W1^T)  (f32 A converted inline)
  k_gemm128<true><<<NN / 32, 256, 0, stream>>>(x, W1b, dis, g);
  k_aggregate<<<NN / 4, 256, 0, stream>>>(meta, csr, dis, g, b1, h1);
  // layer 2
  k_gemm128<false><<<NN / 32, 256, 0, stream>>>(h1, W2b, dis, g);
  k_aggregate<<<NN / 4, 256, 0, stream>>>(meta, csr, dis, g, b2, h2);
  // readout
  k_readout<<<NN / 32, 256, 0, stream>>>(h1, h2, Wrb, br, (float*)d_out);
}

// Round 5
// 397.435 us; speedup vs baseline: 1.4269x; 1.0794x over previous
//
#include <hip/hip_runtime.h>

#define NN 100000
#define NE 1600000
#define HID 128
#define ODIM 64
#define NBK 196          // ceil(NN/512) buckets of 512 nodes
#define BSHIFT 9
#define BGRID 800        // k_bin main blocks (3.1/CU)
#define CVTB 48          // extra k_bin blocks doing weight cvt
#define CHUNK 2000       // NE / BGRID (exact)
#define BITER 8          // ceil(CHUNK/256)
#define BINCAP 12288     // records per bucket region (mean ~9400 incl pad)
#define SMAX 2588        // LDS staging records >= 2000 + 196*3
#define LMAX 647         // line map entries >= SMAX/4

typedef unsigned int u32;
typedef unsigned short u16;
typedef __bf16 bf16x8 __attribute__((ext_vector_type(8)));
typedef float f32x4 __attribute__((ext_vector_type(4)));
typedef float f32x2 __attribute__((ext_vector_type(2)));

__device__ __forceinline__ float bf_lo(u32 p){ return __uint_as_float(p << 16); }
__device__ __forceinline__ float bf_hi(u32 p){ return __uint_as_float(p & 0xffff0000u); }
__device__ __forceinline__ u16 f2bf(float f){
  u32 u = __float_as_uint(f);
  u += 0x7fffu + ((u >> 16) & 1u);   // RTNE
  return (u16)(u >> 16);
}
__device__ __forceinline__ bf16x8 ld8bf(const u16* p){ return *(const bf16x8*)p; }
__device__ __forceinline__ bf16x8 cvt8(const float* p){
  union { bf16x8 v; u16 s[8]; } r;
#pragma unroll
  for (int i = 0; i < 8; i++) r.s[i] = f2bf(p[i]);
  return r.v;
}

// w(mq) = A - B*mq, linear in the 15-bit quantized mean; clip never binds
// (eps in the reference keeps w(mx) = eps/(rng+eps) > 0).
__device__ __forceinline__ void wparams(const u32* minmax, float* A, float* B){
  u32 mnq = 32767u - minmax[0];                // minmax[0] = max(32767-mq)
  u32 mxq = minmax[1];                         // minmax[1] = max(mq)
  u32 rngq = mxq - mnq;
  float inv = rngq ? 1.f / ((float)rngq * (1.f / 32767.f) + 1e-8f) : 0.f;
  *A = 1.f + (float)mnq * (1.f / 32767.f) * inv;
  *B = inv * (1.f / 32767.f);
}

// -- fused edge pass + bin (split 6B records); extra blocks cvt weights.
//    Per-wave privatized bucket counters. Integer minmax (quantized mq).
__global__ __launch_bounds__(256) void k_bin(
    const float* __restrict__ eattr, const int* __restrict__ erow,
    const int* __restrict__ ecol, u32* __restrict__ bcur,
    u32* __restrict__ binA, u16* __restrict__ binM, u32* __restrict__ minmax,
    const float* __restrict__ W1, const float* __restrict__ W2,
    const float* __restrict__ Wr, u16* __restrict__ W1b,
    u16* __restrict__ W2b, u16* __restrict__ Wrb){
  int tid = threadIdx.x;
  if (blockIdx.x >= BGRID){                    // weight-conversion blocks
    int i = (blockIdx.x - BGRID) * 256 + tid;  // 12288 float4 slots
    const float* src; u16* dst; int off;
    if (i < 4096){ src = W1; dst = W1b; off = i; }
    else if (i < 8192){ src = W2; dst = W2b; off = i - 4096; }
    else { src = Wr; dst = Wrb; off = i - 8192; }
    float4 v = ((const float4*)src)[off];
    uint2 o;
    o.x = (u32)f2bf(v.x) | ((u32)f2bf(v.y) << 16);
    o.y = (u32)f2bf(v.z) | ((u32)f2bf(v.w) << 16);
    ((uint2*)dst)[off] = o;
    return;
  }
  __shared__ u32 lcnt4[4 * NBK], wof4[4 * NBK];
  __shared__ u32 lofs[NBK], gb[NBK];
  __shared__ u32 scn[256];
  __shared__ u16 lmap[LMAX];
  __shared__ u32 stageA[SMAX];
  __shared__ u16 stageM[SMAX];
  __shared__ u32 Tt;
  __shared__ u32 sMn[4], sMx[4];
  for (int t = tid; t < 4 * NBK; t += 256) lcnt4[t] = 0;
  __syncthreads();
  int base = blockIdx.x * CHUNK;
  int wid = tid >> 6, lane = tid & 63;
  u32 lmn = 0, lmx = 0;                        // lmn holds max(32767-mq)
  u32 pk[BITER], sd[BITER], mq8[BITER];
#pragma unroll
  for (int it = 0; it < BITER; it++){
    int idx = it * 256 + tid;
    u32 p = 0xFFFFFFFFu, srcd = 0, mq = 0;
    if (idx < CHUNK){
      int e = base + idx;
      float4 a = ((const float4*)eattr)[e];
      float m = 0.25f * (a.x + a.y + a.z + a.w);
      mq = (u32)(m * 32767.f + 0.5f);          // m in [0,1) -> fits 15 bits
      lmn = max(lmn, 32767u - mq); lmx = max(lmx, mq);
      int c = ecol[e];
      u32 s = (u32)erow[e]; if (s >= NN) s = 0;  // never triggers (randint<NN)
      if ((u32)c < NN){
        u32 b = (u32)c >> BSHIFT;
        u32 r = atomicAdd(&lcnt4[wid * NBK + b], 1u);   // r < 512, fits 12b
        p = (b << 21) | r;
        srcd = s | (((u32)c & 511u) << 17);    // src:17 | d:9 (bits 26+ zero)
      }
    }
    pk[it] = p; sd[it] = srcd; mq8[it] = mq;
  }
  __syncthreads();
  // combine per-wave counts; pad-to-4 scan; global region alloc; line map
  u32 na = 0, n = 0;
  if (tid < NBK){
    u32 n0 = lcnt4[tid], n1 = lcnt4[NBK + tid];
    u32 n2 = lcnt4[2 * NBK + tid], n3 = lcnt4[3 * NBK + tid];
    n = n0 + n1 + n2 + n3;
    na = (n + 3u) & ~3u;
    wof4[tid] = 0; wof4[NBK + tid] = n0;
    wof4[2 * NBK + tid] = n0 + n1; wof4[3 * NBK + tid] = n0 + n1 + n2;
  }
  scn[tid] = na; __syncthreads();
  for (int s = 1; s < 256; s <<= 1){
    u32 t = (tid >= s) ? scn[tid - s] : 0;
    __syncthreads();
    scn[tid] += t;
    __syncthreads();
  }
  u32 ex = scn[tid] - na;
  if (tid < NBK){
    lofs[tid] = ex;
    u32 g = 0x80000000u;
    if (na){
      u32 gl = atomicAdd(&bcur[tid], na);      // bcur 0-init by memset
      if (gl + na <= BINCAP) g = (u32)tid * BINCAP + gl;
    }
    gb[tid] = g;
    for (u32 l = ex >> 2; l < (ex + na) >> 2; l++) lmap[l] = (u16)tid;
    for (u32 k = n; k < na; k++){ stageA[ex + k] = 0xFFFFFFFFu; stageM[ex + k] = 0; }
  }
  if (tid == 255) Tt = scn[255];
  __syncthreads();
  // place records bucket-major in LDS
#pragma unroll
  for (int it = 0; it < BITER; it++){
    u32 p = pk[it];
    if (p == 0xFFFFFFFFu) continue;
    u32 b = p >> 21;
    u32 slot = lofs[b] + wof4[wid * NBK + b] + (p & 4095u);
    stageA[slot] = sd[it];
    stageM[slot] = (u16)mq8[it];
  }
  __syncthreads();
  // stream out: consecutive threads -> consecutive slots in 4-record runs
  u32 T = Tt;
  for (u32 i = tid; i < T; i += 256){
    u32 b = lmap[i >> 2];
    u32 g = gb[b];
    if (g != 0x80000000u){
      u32 o = g + (i - lofs[b]);
      binA[o] = stageA[i];
      binM[o] = stageM[i];
    }
  }
  // integer min/max reduce + global update (0-init compatible encoding)
  for (int off = 32; off; off >>= 1){
    lmn = max(lmn, (u32)__shfl_xor((int)lmn, off));
    lmx = max(lmx, (u32)__shfl_xor((int)lmx, off));
  }
  if (lane == 0){ sMn[wid] = lmn; sMx[wid] = lmx; }
  __syncthreads();
  if (tid == 0){
    u32 mn = max(max(sMn[0], sMn[1]), max(sMn[2], sMn[3]));
    u32 mx = max(max(sMx[0], sMx[1]), max(sMx[2], sMx[3]));
    atomicMax(&minmax[0], mn);
    atomicMax(&minmax[1], mx);
  }
}

// -- scatter: count+scan+scatter in one kernel, two passes over bucket
//    region (2nd pass L2-hot). 7 KB LDS. Sum(w) is linear in (c, sum mq).
__global__ __launch_bounds__(1024) void k_scatter(
    const u32* __restrict__ bcur, const u32* __restrict__ binA,
    const u16* __restrict__ binM, const u32* __restrict__ minmax,
    u32* __restrict__ csr, u32* __restrict__ meta, float* __restrict__ dis){
  __shared__ u32 cntL[512], sumL[512], curL[512];
  __shared__ u32 wtot[8];
  int b = blockIdx.x, tid = threadIdx.x;
  int bb = b * BINCAP;
  int nrec = (int)min(bcur[b], (u32)BINCAP);
  if (tid < 512){ cntL[tid] = 0; sumL[tid] = 0; }
  __syncthreads();
  for (int i = tid; i < nrec; i += 1024){
    u32 a = binA[bb + i];
    if (a == 0xFFFFFFFFu) continue;            // pad sentinel
    u32 d = (a >> 17) & 511u;
    u32 mq = binM[bb + i];
    atomicAdd(&cntL[d], 1u);
    atomicAdd(&sumL[d], mq);
  }
  __syncthreads();
  float A, B; wparams(minmax, &A, &B);
  int wid = tid >> 6, lane = tid & 63;
  u32 v = 0, incl = 0;
  if (tid < 512){ v = cntL[tid]; incl = v; }
  for (int off = 1; off < 64; off <<= 1){
    u32 t = (u32)__shfl_up((int)incl, off);
    if (lane >= off) incl += t;
  }
  if (tid < 512 && lane == 63) wtot[wid] = incl;
  __syncthreads();
  if (tid < 512){
    u32 pre = 0;
#pragma unroll
    for (int k = 0; k < 8; k++) pre += (k < wid) ? wtot[k] : 0u;
    u32 ex = pre + incl - v;
    curL[tid] = (u32)bb + ex;
    int node = (b << BSHIFT) + tid;
    if (node < NN){
      meta[node] = ((u32)bb + ex) | (v << 22); // rs<2.41M fits 22b; cnt<1024
      float sw = A * (float)v - B * (float)sumL[tid];   // sum of weights
      dis[node] = rsqrtf(1.f + sw);
    }
  }
  __syncthreads();
  for (int i = tid; i < nrec; i += 1024){
    u32 a = binA[bb + i];
    if (a == 0xFFFFFFFFu) continue;
    u32 d = (a >> 17) & 511u;
    u32 mq = binM[bb + i];
    u32 pos = atomicAdd(&curL[d], 1u);         // LDS returning atomic
    csr[pos] = (a & 0x1FFFFu) | (mq << 17);    // src:17 | mq:15
  }
}

// -- bf16 MFMA GEMM: G[M,128] = dis[m]*(A[M,128] @ Bt[128,128]^T) ---------
// One block = 32 rows x ALL 128 cols (wave: 2 m-tiles x 2 n-tiles).
template <bool A_F32>
__global__ __launch_bounds__(256) void k_gemm128(
    const void* __restrict__ Av, const u16* __restrict__ Bt,
    const float* __restrict__ dis, u16* __restrict__ G){
  int wave = threadIdx.x >> 6, lane = threadIdx.x & 63;
  int m0 = blockIdx.x * 32;
  int m = lane & 15, q = lane >> 4;
  const float* a0f = (const float*)Av + (size_t)(m0 + m) * HID;
  const float* a1f = a0f + (size_t)16 * HID;
  const u16*   a0b = (const u16*)Av   + (size_t)(m0 + m) * HID;
  const u16*   a1b = a0b + (size_t)16 * HID;
  const u16* brow0 = Bt + (size_t)(wave * 16 + m) * HID;
  const u16* brow1 = brow0 + (size_t)64 * HID;
  f32x4 acc00 = {0.f,0.f,0.f,0.f}, acc01 = {0.f,0.f,0.f,0.f};
  f32x4 acc10 = {0.f,0.f,0.f,0.f}, acc11 = {0.f,0.f,0.f,0.f};
#pragma unroll
  for (int kb = 0; kb < HID; kb += 32){
    bf16x8 af0 = A_F32 ? cvt8(a0f + kb + q * 8) : ld8bf(a0b + kb + q * 8);
    bf16x8 af1 = A_F32 ? cvt8(a1f + kb + q * 8) : ld8bf(a1b + kb + q * 8);
    bf16x8 bf0 = ld8bf(brow0 + kb + q * 8);
    bf16x8 bf1 = ld8bf(brow1 + kb + q * 8);
    acc00 = __builtin_amdgcn_mfma_f32_16x16x32_bf16(af0, bf0, acc00, 0, 0, 0);
    acc01 = __builtin_amdgcn_mfma_f32_16x16x32_bf16(af0, bf1, acc01, 0, 0, 0);
    acc10 = __builtin_amdgcn_mfma_f32_16x16x32_bf16(af1, bf0, acc10, 0, 0, 0);
    acc11 = __builtin_amdgcn_mfma_f32_16x16x32_bf16(af1, bf1, acc11, 0, 0, 0);
  }
  u16* crow0 = G + (size_t)(m0 + q * 4) * HID + wave * 16 + m;
  u16* crow1 = crow0 + (size_t)16 * HID;
#pragma unroll
  for (int r = 0; r < 4; r++){
    float d0 = dis[m0 + q * 4 + r];
    float d1 = dis[m0 + 16 + q * 4 + r];
    crow0[(size_t)r * HID]      = f2bf(acc00[r] * d0);
    crow0[(size_t)r * HID + 64] = f2bf(acc01[r] * d0);
    crow1[(size_t)r * HID]      = f2bf(acc10[r] * d1);
    crow1[(size_t)r * HID + 64] = f2bf(acc11[r] * d1);
  }
}

// ------- aggregation: wave/node, scalar csr records, w = A - B*mq --------
// h_i = relu( dis_i * (sum_e w_e * g[src_e] + g_i) + b )
__global__ __launch_bounds__(256) void k_aggregate(
    const u32* __restrict__ meta, const u32* __restrict__ csr,
    const float* __restrict__ dis, const u32* __restrict__ minmax,
    const u16* __restrict__ g, const float* __restrict__ bias,
    u16* __restrict__ hout){
  int node = __builtin_amdgcn_readfirstlane(
      (int)(blockIdx.x * 4 + (threadIdx.x >> 6)));
  int lane = threadIdx.x & 63;
  const u32* gp = (const u32*)g;
  u32 sv = gp[((size_t)node << 6) + lane];     // self row, issued early
  u32 mw = meta[node];                          // uniform -> scalar load
  float di = dis[node];                         // uniform -> scalar load
  float A, B; wparams(minmax, &A, &B);
  u32 s = mw & 0x3FFFFFu;
  int c = (int)(mw >> 22);
  const u32* cp = csr + s;
  f32x2 acc = {0.f, 0.f};
  int j = 0;
  // full 16-edge chunks: 16 gathers in flight, no conditionals
  for (; j + 16 <= c; j += 16){
    u32 p[16];
#pragma unroll
    for (int t = 0; t < 16; t++)
      p[t] = __builtin_amdgcn_readfirstlane(cp[j + t]);
    u32 pv[16];
#pragma unroll
    for (int t = 0; t < 16; t++)
      pv[t] = gp[(size_t)(p[t] & 0x1FFFFu) * 64u + lane];
#pragma unroll
    for (int t = 0; t < 16; t++){
      float wf = A - B * (float)(p[t] >> 17);
      f32x2 val = {bf_lo(pv[t]), bf_hi(pv[t])};
      f32x2 w2 = {wf, wf};
      acc += w2 * val;
    }
  }
  // masked 8-edge chunks for the tail (src->0, w->0 beyond c)
  for (; j < c; j += 8){
    u32 p[8];
#pragma unroll
    for (int t = 0; t < 8; t++)
      p[t] = __builtin_amdgcn_readfirstlane(cp[j + t]);  // bucket slack: safe
    u32 st[8]; float wv[8];
#pragma unroll
    for (int t = 0; t < 8; t++){
      bool ok = (j + t) < c;                   // wave-uniform condition
      st[t] = ok ? (p[t] & 0x1FFFFu) : 0u;
      wv[t] = ok ? (A - B * (float)(p[t] >> 17)) : 0.f;
    }
    u32 pv[8];
#pragma unroll
    for (int t = 0; t < 8; t++)
      pv[t] = gp[(size_t)st[t] * 64u + lane];
#pragma unroll
    for (int t = 0; t < 8; t++){
      f32x2 val = {bf_lo(pv[t]), bf_hi(pv[t])};
      f32x2 w2 = {wv[t], wv[t]};
      acc += w2 * val;
    }
  }
  float2 bv = ((const float2*)bias)[lane];
  f32x2 selfv = {bf_lo(sv), bf_hi(sv)};
  float o0 = fmaxf((acc.x + selfv.x) * di + bv.x, 0.f);
  float o1 = fmaxf((acc.y + selfv.y) * di + bv.y, 0.f);
  ((u32*)hout)[((size_t)node << 6) + lane] = (u32)f2bf(o0) | ((u32)f2bf(o1) << 16);
}

// -- readout: out[M,64] = [h1|h2] @ Wr^T + br (f32 out), 32 rows/block ----
__global__ __launch_bounds__(256) void k_readout(
    const u16* __restrict__ h1, const u16* __restrict__ h2,
    const u16* __restrict__ Wrb, const float* __restrict__ br, float* __restrict__ out){
  int wave = threadIdx.x >> 6, lane = threadIdx.x & 63;
  int m0 = blockIdx.x * 32;
  int n0 = wave * 16;
  int m = lane & 15, q = lane >> 4;
  const u16* a10 = h1 + (size_t)(m0 + m) * HID;
  const u16* a11 = a10 + (size_t)16 * HID;
  const u16* a20 = h2 + (size_t)(m0 + m) * HID;
  const u16* a21 = a20 + (size_t)16 * HID;
  const u16* b  = Wrb + (size_t)(n0 + m) * (2 * HID);
  f32x4 acc0 = {0.f,0.f,0.f,0.f}, acc1 = {0.f,0.f,0.f,0.f};
#pragma unroll
  for (int kb = 0; kb < HID; kb += 32){
    bf16x8 bf = ld8bf(b + kb + q * 8);
    acc0 = __builtin_amdgcn_mfma_f32_16x16x32_bf16(ld8bf(a10 + kb + q * 8), bf, acc0, 0, 0, 0);
    acc1 = __builtin_amdgcn_mfma_f32_16x16x32_bf16(ld8bf(a11 + kb + q * 8), bf, acc1, 0, 0, 0);
  }
#pragma unroll
  for (int kb = 0; kb < HID; kb += 32){
    bf16x8 bf = ld8bf(b + HID + kb + q * 8);
    acc0 = __builtin_amdgcn_mfma_f32_16x16x32_bf16(ld8bf(a20 + kb + q * 8), bf, acc0, 0, 0, 0);
    acc1 = __builtin_amdgcn_mfma_f32_16x16x32_bf16(ld8bf(a21 + kb + q * 8), bf, acc1, 0, 0, 0);
  }
  float bias = br[n0 + m];
  float* crow0 = out + (size_t)(m0 + q * 4) * ODIM + n0 + m;
  float* crow1 = crow0 + (size_t)16 * ODIM;
#pragma unroll
  for (int r = 0; r < 4; r++){
    crow0[(size_t)r * ODIM] = acc0[r] + bias;
    crow1[(size_t)r * ODIM] = acc1[r] + bias;
  }
}

// ---------------- launch --------------------------------------------------
extern "C" void kernel_launch(void* const* d_in, const int* in_sizes, int n_in,
                              void* d_out, int out_size, void* d_ws, size_t ws_size,
                              hipStream_t stream){
  const float* x     = (const float*)d_in[0];
  const int*   eidx  = (const int*)d_in[1];
  const float* eattr = (const float*)d_in[2];
  const float* W1    = (const float*)d_in[3];
  const float* b1    = (const float*)d_in[4];
  const float* W2    = (const float*)d_in[5];
  const float* b2    = (const float*)d_in[6];
  const float* Wr    = (const float*)d_in[7];
  const float* br    = (const float*)d_in[8];
  const int* erow  = eidx;        // edge_index[0]
  const int* ecol  = eidx + NE;   // edge_index[1]

  char* w = (char*)d_ws;
  auto carve = [&](size_t bytes) -> void* {
    void* p = (void*)w;
    w += (bytes + 255) & ~(size_t)255;
    return p;
  };
  u32* csr       = (u32*)carve((size_t)NBK * BINCAP * 4);  // bucket-padded, 4B recs
  u32* bcur      = (u32*)carve(1024);             // bcur+minmax contiguous memset
  u32* minmax    = (u32*)carve(256);
  u32* meta      = (u32*)carve((size_t)NN * 4);   // rs|cnt<<22 packed
  float* dis     = (float*)carve((size_t)NN * 4);
  u16* W1b       = (u16*)carve((size_t)HID * HID * 2);
  u16* W2b       = (u16*)carve((size_t)HID * HID * 2);
  u16* Wrb       = (u16*)carve((size_t)ODIM * 2 * HID * 2);
  u16* g         = (u16*)carve((size_t)NN * HID * 2);
  u16* h1        = (u16*)carve((size_t)NN * HID * 2);
  u16* h2        = (u16*)carve((size_t)NN * HID * 2);
  // bin arrays alias h2 (14.4 MB <= 25.6 MB); dead before layer-2 writes h2
  u32* binA      = (u32*)h2;
  u16* binM      = (u16*)((char*)h2 + (size_t)NBK * BINCAP * 4);

  hipMemsetAsync(bcur, 0, 1280, stream);          // bcur + minmax
  k_bin<<<BGRID + CVTB, 256, 0, stream>>>(eattr, erow, ecol, bcur, binA, binM,
                                          minmax, W1, W2, Wr, W1b, W2b, Wrb);
  k_scatter<<<NBK, 1024, 0, stream>>>(bcur, binA, binM, minmax, csr, meta, dis);

  // layer 1: g = dis * (x @ W1^T)  (f32 A converted inline)
  k_gemm128<true><<<NN / 32, 256, 0, stream>>>(x, W1b, dis, g);
  k_aggregate<<<NN / 4, 256, 0, stream>>>(meta, csr, dis, minmax, g, b1, h1);
  // layer 2
  k_gemm128<false><<<NN / 32, 256, 0, stream>>>(h1, W2b, dis, g);
  k_aggregate<<<NN / 4, 256, 0, stream>>>(meta, csr, dis, minmax, g, b2, h2);
  // readout
  k_readout<<<NN / 32, 256, 0, stream>>>(h1, h2, Wrb, br, (float*)d_out);
}

// Round 6
// 390.521 us; speedup vs baseline: 1.4522x; 1.0177x over previous
//
#include <hip/hip_runtime.h>

#define NN 100000
#define NE 1600000
#define HID 128
#define ODIM 64
#define NBK 196          // ceil(NN/512) buckets of 512 nodes
#define BSHIFT 9
#define BGRID 800        // k_front bin blocks (3.1/CU)
#define CVTB 32          // k_front weight-cvt blocks (W2, Wr)
#define GEMMB 3125       // k_front gemm blocks (NN/32)
#define CHUNK 2000       // NE / BGRID (exact)
#define BITER 8          // ceil(CHUNK/256)
#define BINCAP 12288     // records per bucket region (mean ~8200, big slack)
#define SMAX 2588        // LDS staging records >= 2000 + 196*3
#define LMAX 647         // line map entries >= SMAX/4

typedef unsigned int u32;
typedef unsigned short u16;
typedef __bf16 bf16x8 __attribute__((ext_vector_type(8)));
typedef float f32x4 __attribute__((ext_vector_type(4)));
typedef float f32x2 __attribute__((ext_vector_type(2)));

__device__ __forceinline__ float bf_lo(u32 p){ return __uint_as_float(p << 16); }
__device__ __forceinline__ float bf_hi(u32 p){ return __uint_as_float(p & 0xffff0000u); }
__device__ __forceinline__ u16 f2bf(float f){
  u32 u = __float_as_uint(f);
  u += 0x7fffu + ((u >> 16) & 1u);   // RTNE
  return (u16)(u >> 16);
}
__device__ __forceinline__ bf16x8 ld8bf(const u16* p){ return *(const bf16x8*)p; }
__device__ __forceinline__ bf16x8 cvt8(const float* p){
  union { bf16x8 v; u16 s[8]; } r;
#pragma unroll
  for (int i = 0; i < 8; i++) r.s[i] = f2bf(p[i]);
  return r.v;
}

// w(mq) = A - B*mq, linear in the 15-bit quantized mean; clip never binds
// (eps in the reference keeps w(mx) = eps/(rng+eps) > 0).
__device__ __forceinline__ void wparams(const u32* minmax, float* A, float* B){
  u32 mnq = 32767u - minmax[0];                // minmax[0] = max(32767-mq)
  u32 mxq = minmax[1];                         // minmax[1] = max(mq)
  u32 rngq = mxq - mnq;
  float inv = rngq ? 1.f / ((float)rngq * (1.f / 32767.f) + 1e-8f) : 0.f;
  *A = 1.f + (float)mnq * (1.f / 32767.f) * inv;
  *B = inv * (1.f / 32767.f);
}

// -- front kernel: [0,BGRID) edge bin | [BGRID,+CVTB) weight cvt |
//    [BGRID+CVTB,+GEMMB) layer-1 gemm g_raw = x @ W1^T (bf16 inline, NO dis;
//    dis is folded into aggregate<FD=true>). gemm blocks backfill the idle
//    CUs of the latency-bound bin phase (bin: 3% VALU, 14% HBM in R4).
__global__ __launch_bounds__(256, 4) void k_front(
    const float* __restrict__ eattr, const int* __restrict__ erow,
    const int* __restrict__ ecol, u32* __restrict__ bcur,
    u32* __restrict__ binA, u16* __restrict__ binM, u32* __restrict__ minmax,
    const float* __restrict__ x, const float* __restrict__ W1,
    const float* __restrict__ W2, const float* __restrict__ Wr,
    u16* __restrict__ W2b, u16* __restrict__ Wrb, u16* __restrict__ graw){
  int tid = threadIdx.x;
  int bid = blockIdx.x;
  if (bid >= BGRID + CVTB){                    // ---- layer-1 gemm blocks ----
    int gblk = bid - BGRID - CVTB;
    int wave = tid >> 6, lane = tid & 63;
    int m0 = gblk * 32;
    int m = lane & 15, q = lane >> 4;
    const float* a0f = x + (size_t)(m0 + m) * HID;
    const float* a1f = a0f + (size_t)16 * HID;
    const float* brow0 = W1 + (size_t)(wave * 16 + m) * HID;  // f32, L2-hot
    const float* brow1 = brow0 + (size_t)64 * HID;
    f32x4 acc00 = {0.f,0.f,0.f,0.f}, acc01 = {0.f,0.f,0.f,0.f};
    f32x4 acc10 = {0.f,0.f,0.f,0.f}, acc11 = {0.f,0.f,0.f,0.f};
#pragma unroll
    for (int kb = 0; kb < HID; kb += 32){
      bf16x8 af0 = cvt8(a0f + kb + q * 8);
      bf16x8 af1 = cvt8(a1f + kb + q * 8);
      bf16x8 bf0 = cvt8(brow0 + kb + q * 8);
      bf16x8 bf1 = cvt8(brow1 + kb + q * 8);
      acc00 = __builtin_amdgcn_mfma_f32_16x16x32_bf16(af0, bf0, acc00, 0, 0, 0);
      acc01 = __builtin_amdgcn_mfma_f32_16x16x32_bf16(af0, bf1, acc01, 0, 0, 0);
      acc10 = __builtin_amdgcn_mfma_f32_16x16x32_bf16(af1, bf0, acc10, 0, 0, 0);
      acc11 = __builtin_amdgcn_mfma_f32_16x16x32_bf16(af1, bf1, acc11, 0, 0, 0);
    }
    u16* crow0 = graw + (size_t)(m0 + q * 4) * HID + wave * 16 + m;
    u16* crow1 = crow0 + (size_t)16 * HID;
#pragma unroll
    for (int r = 0; r < 4; r++){
      crow0[(size_t)r * HID]      = f2bf(acc00[r]);
      crow0[(size_t)r * HID + 64] = f2bf(acc01[r]);
      crow1[(size_t)r * HID]      = f2bf(acc10[r]);
      crow1[(size_t)r * HID + 64] = f2bf(acc11[r]);
    }
    return;
  }
  if (bid >= BGRID){                           // ---- weight-cvt blocks ----
    int i = (bid - BGRID) * 256 + tid;         // 8192 float4 slots (W2, Wr)
    const float* src; u16* dst; int off;
    if (i < 4096){ src = W2; dst = W2b; off = i; }
    else { src = Wr; dst = Wrb; off = i - 4096; }
    float4 v = ((const float4*)src)[off];
    uint2 o;
    o.x = (u32)f2bf(v.x) | ((u32)f2bf(v.y) << 16);
    o.y = (u32)f2bf(v.z) | ((u32)f2bf(v.w) << 16);
    ((uint2*)dst)[off] = o;
    return;
  }
  // -------------------------- bin blocks ---------------------------------
  __shared__ u32 lcnt4[4 * NBK], wof4[4 * NBK];
  __shared__ u32 lofs[NBK], gb[NBK];
  __shared__ u32 scn[256];
  __shared__ u16 lmap[LMAX];
  __shared__ u32 stageA[SMAX];
  __shared__ u16 stageM[SMAX];
  __shared__ u32 Tt;
  __shared__ u32 sMn[4], sMx[4];
  for (int t = tid; t < 4 * NBK; t += 256) lcnt4[t] = 0;
  __syncthreads();
  int base = bid * CHUNK;
  int wid = tid >> 6, lane = tid & 63;
  u32 lmn = 0, lmx = 0;                        // lmn holds max(32767-mq)
  u32 pk[BITER], sd[BITER], mq8[BITER];
#pragma unroll
  for (int it = 0; it < BITER; it++){
    int idx = it * 256 + tid;
    u32 p = 0xFFFFFFFFu, srcd = 0, mq = 0;
    if (idx < CHUNK){
      int e = base + idx;
      float4 a = ((const float4*)eattr)[e];
      float m = 0.25f * (a.x + a.y + a.z + a.w);
      mq = (u32)(m * 32767.f + 0.5f);          // m in [0,1) -> fits 15 bits
      lmn = max(lmn, 32767u - mq); lmx = max(lmx, mq);
      int c = ecol[e];
      u32 s = (u32)erow[e]; if (s >= NN) s = 0;  // never triggers (randint<NN)
      if ((u32)c < NN){
        u32 b = (u32)c >> BSHIFT;
        u32 r = atomicAdd(&lcnt4[wid * NBK + b], 1u);   // r < 512, fits 12b
        p = (b << 21) | r;
        srcd = s | (((u32)c & 511u) << 17);    // src:17 | d:9 (bits 26+ zero)
      }
    }
    pk[it] = p; sd[it] = srcd; mq8[it] = mq;
  }
  __syncthreads();
  // combine per-wave counts; pad-to-4 scan; global region alloc; line map
  u32 na = 0, n = 0;
  if (tid < NBK){
    u32 n0 = lcnt4[tid], n1 = lcnt4[NBK + tid];
    u32 n2 = lcnt4[2 * NBK + tid], n3 = lcnt4[3 * NBK + tid];
    n = n0 + n1 + n2 + n3;
    na = (n + 3u) & ~3u;
    wof4[tid] = 0; wof4[NBK + tid] = n0;
    wof4[2 * NBK + tid] = n0 + n1; wof4[3 * NBK + tid] = n0 + n1 + n2;
  }
  scn[tid] = na; __syncthreads();
  for (int s = 1; s < 256; s <<= 1){
    u32 t = (tid >= s) ? scn[tid - s] : 0;
    __syncthreads();
    scn[tid] += t;
    __syncthreads();
  }
  u32 ex = scn[tid] - na;
  if (tid < NBK){
    lofs[tid] = ex;
    u32 g = 0x80000000u;
    if (na){
      u32 gl = atomicAdd(&bcur[tid], na);      // bcur 0-init by memset
      if (gl + na <= BINCAP) g = (u32)tid * BINCAP + gl;
    }
    gb[tid] = g;
    for (u32 l = ex >> 2; l < (ex + na) >> 2; l++) lmap[l] = (u16)tid;
    for (u32 k = n; k < na; k++){ stageA[ex + k] = 0xFFFFFFFFu; stageM[ex + k] = 0; }
  }
  if (tid == 255) Tt = scn[255];
  __syncthreads();
  // place records bucket-major in LDS
#pragma unroll
  for (int it = 0; it < BITER; it++){
    u32 p = pk[it];
    if (p == 0xFFFFFFFFu) continue;
    u32 b = p >> 21;
    u32 slot = lofs[b] + wof4[wid * NBK + b] + (p & 4095u);
    stageA[slot] = sd[it];
    stageM[slot] = (u16)mq8[it];
  }
  __syncthreads();
  // stream out: consecutive threads -> consecutive slots in 4-record runs
  u32 T = Tt;
  for (u32 i = tid; i < T; i += 256){
    u32 b = lmap[i >> 2];
    u32 g = gb[b];
    if (g != 0x80000000u){
      u32 o = g + (i - lofs[b]);
      binA[o] = stageA[i];
      binM[o] = stageM[i];
    }
  }
  // integer min/max reduce + global update (0-init compatible encoding)
  for (int off = 32; off; off >>= 1){
    lmn = max(lmn, (u32)__shfl_xor((int)lmn, off));
    lmx = max(lmx, (u32)__shfl_xor((int)lmx, off));
  }
  if (lane == 0){ sMn[wid] = lmn; sMx[wid] = lmx; }
  __syncthreads();
  if (tid == 0){
    u32 mn = max(max(sMn[0], sMn[1]), max(sMn[2], sMn[3]));
    u32 mx = max(max(sMx[0], sMx[1]), max(sMx[2], sMx[3]));
    atomicMax(&minmax[0], mn);
    atomicMax(&minmax[1], mx);
  }
}

// -- scatter: count+scan+scatter in one kernel, two passes over bucket
//    region (2nd pass L2-hot). 7 KB LDS. Sum(w) is linear in (c, sum mq).
__global__ __launch_bounds__(1024) void k_scatter(
    const u32* __restrict__ bcur, const u32* __restrict__ binA,
    const u16* __restrict__ binM, const u32* __restrict__ minmax,
    u32* __restrict__ csr, u32* __restrict__ meta, float* __restrict__ dis){
  __shared__ u32 cntL[512], sumL[512], curL[512];
  __shared__ u32 wtot[8];
  int b = blockIdx.x, tid = threadIdx.x;
  int bb = b * BINCAP;
  int nrec = (int)min(bcur[b], (u32)BINCAP);
  if (tid < 512){ cntL[tid] = 0; sumL[tid] = 0; }
  __syncthreads();
  for (int i = tid; i < nrec; i += 1024){
    u32 a = binA[bb + i];
    if (a == 0xFFFFFFFFu) continue;            // pad sentinel
    u32 d = (a >> 17) & 511u;
    u32 mq = binM[bb + i];
    atomicAdd(&cntL[d], 1u);
    atomicAdd(&sumL[d], mq);
  }
  __syncthreads();
  float A, B; wparams(minmax, &A, &B);
  int wid = tid >> 6, lane = tid & 63;
  u32 v = 0, incl = 0;
  if (tid < 512){ v = cntL[tid]; incl = v; }
  for (int off = 1; off < 64; off <<= 1){
    u32 t = (u32)__shfl_up((int)incl, off);
    if (lane >= off) incl += t;
  }
  if (tid < 512 && lane == 63) wtot[wid] = incl;
  __syncthreads();
  if (tid < 512){
    u32 pre = 0;
#pragma unroll
    for (int k = 0; k < 8; k++) pre += (k < wid) ? wtot[k] : 0u;
    u32 ex = pre + incl - v;
    curL[tid] = (u32)bb + ex;
    int node = (b << BSHIFT) + tid;
    if (node < NN){
      meta[node] = ((u32)bb + ex) | (v << 22); // rs<2.41M fits 22b; cnt<1024
      float sw = A * (float)v - B * (float)sumL[tid];   // sum of weights
      dis[node] = rsqrtf(1.f + sw);
    }
  }
  __syncthreads();
  for (int i = tid; i < nrec; i += 1024){
    u32 a = binA[bb + i];
    if (a == 0xFFFFFFFFu) continue;
    u32 d = (a >> 17) & 511u;
    u32 mq = binM[bb + i];
    u32 pos = atomicAdd(&curL[d], 1u);         // LDS returning atomic
    csr[pos] = (a & 0x1FFFFu) | (mq << 17);    // src:17 | mq:15
  }
}

// -- bf16 MFMA GEMM (layer 2): G = dis[m]*(A[M,128] @ Bt[128,128]^T) ------
__global__ __launch_bounds__(256) void k_gemm128(
    const u16* __restrict__ Ab, const u16* __restrict__ Bt,
    const float* __restrict__ dis, u16* __restrict__ G){
  int wave = threadIdx.x >> 6, lane = threadIdx.x & 63;
  int m0 = blockIdx.x * 32;
  int m = lane & 15, q = lane >> 4;
  const u16* a0b = Ab + (size_t)(m0 + m) * HID;
  const u16* a1b = a0b + (size_t)16 * HID;
  const u16* brow0 = Bt + (size_t)(wave * 16 + m) * HID;
  const u16* brow1 = brow0 + (size_t)64 * HID;
  f32x4 acc00 = {0.f,0.f,0.f,0.f}, acc01 = {0.f,0.f,0.f,0.f};
  f32x4 acc10 = {0.f,0.f,0.f,0.f}, acc11 = {0.f,0.f,0.f,0.f};
#pragma unroll
  for (int kb = 0; kb < HID; kb += 32){
    bf16x8 af0 = ld8bf(a0b + kb + q * 8);
    bf16x8 af1 = ld8bf(a1b + kb + q * 8);
    bf16x8 bf0 = ld8bf(brow0 + kb + q * 8);
    bf16x8 bf1 = ld8bf(brow1 + kb + q * 8);
    acc00 = __builtin_amdgcn_mfma_f32_16x16x32_bf16(af0, bf0, acc00, 0, 0, 0);
    acc01 = __builtin_amdgcn_mfma_f32_16x16x32_bf16(af0, bf1, acc01, 0, 0, 0);
    acc10 = __builtin_amdgcn_mfma_f32_16x16x32_bf16(af1, bf0, acc10, 0, 0, 0);
    acc11 = __builtin_amdgcn_mfma_f32_16x16x32_bf16(af1, bf1, acc11, 0, 0, 0);
  }
  u16* crow0 = G + (size_t)(m0 + q * 4) * HID + wave * 16 + m;
  u16* crow1 = crow0 + (size_t)16 * HID;
#pragma unroll
  for (int r = 0; r < 4; r++){
    float d0 = dis[m0 + q * 4 + r];
    float d1 = dis[m0 + 16 + q * 4 + r];
    crow0[(size_t)r * HID]      = f2bf(acc00[r] * d0);
    crow0[(size_t)r * HID + 64] = f2bf(acc01[r] * d0);
    crow1[(size_t)r * HID]      = f2bf(acc10[r] * d1);
    crow1[(size_t)r * HID + 64] = f2bf(acc11[r] * d1);
  }
}

// ------- aggregation: wave/node, scalar csr records, w = A - B*mq --------
// FD=false: g has dis folded: h = relu(di*(acc + self) + b)
// FD=true : g is raw x@W1:   h = relu(di*(acc' + di*self) + b),
//           acc' = sum w_e * dis[src] * g_raw[src]  (dis[src] scalar-loaded)
template <bool FD>
__global__ __launch_bounds__(256) void k_aggregate(
    const u32* __restrict__ meta, const u32* __restrict__ csr,
    const float* __restrict__ dis, const u32* __restrict__ minmax,
    const u16* __restrict__ g, const float* __restrict__ bias,
    u16* __restrict__ hout){
  int node = __builtin_amdgcn_readfirstlane(
      (int)(blockIdx.x * 4 + (threadIdx.x >> 6)));
  int lane = threadIdx.x & 63;
  const u32* gp = (const u32*)g;
  u32 sv = gp[((size_t)node << 6) + lane];     // self row, issued early
  u32 mw = meta[node];                          // uniform -> scalar load
  float di = dis[node];                         // uniform -> scalar load
  float A, B; wparams(minmax, &A, &B);
  u32 s = mw & 0x3FFFFFu;
  int c = (int)(mw >> 22);
  const u32* cp = csr + s;
  f32x2 acc = {0.f, 0.f};
  int j = 0;
  // full 16-edge chunks: 16 gathers in flight, no conditionals
  for (; j + 16 <= c; j += 16){
    u32 p[16];
#pragma unroll
    for (int t = 0; t < 16; t++)
      p[t] = __builtin_amdgcn_readfirstlane(cp[j + t]);
    u32 pv[16];
#pragma unroll
    for (int t = 0; t < 16; t++)
      pv[t] = gp[(size_t)(p[t] & 0x1FFFFu) * 64u + lane];
#pragma unroll
    for (int t = 0; t < 16; t++){
      float wf = A - B * (float)(p[t] >> 17);
      if (FD) wf *= dis[p[t] & 0x1FFFFu];      // uniform idx -> scalar load
      f32x2 val = {bf_lo(pv[t]), bf_hi(pv[t])};
      f32x2 w2 = {wf, wf};
      acc += w2 * val;
    }
  }
  // masked 8-edge chunks for the tail (src->0, w->0 beyond c)
  for (; j < c; j += 8){
    u32 p[8];
#pragma unroll
    for (int t = 0; t < 8; t++)
      p[t] = __builtin_amdgcn_readfirstlane(cp[j + t]);  // bucket slack: safe
    u32 st[8]; float wv[8];
#pragma unroll
    for (int t = 0; t < 8; t++){
      bool ok = (j + t) < c;                   // wave-uniform condition
      st[t] = ok ? (p[t] & 0x1FFFFu) : 0u;
      float wf = A - B * (float)(p[t] >> 17);
      if (FD) wf *= dis[st[t]];
      wv[t] = ok ? wf : 0.f;
    }
    u32 pv[8];
#pragma unroll
    for (int t = 0; t < 8; t++)
      pv[t] = gp[(size_t)st[t] * 64u + lane];
#pragma unroll
    for (int t = 0; t < 8; t++){
      f32x2 val = {bf_lo(pv[t]), bf_hi(pv[t])};
      f32x2 w2 = {wv[t], wv[t]};
      acc += w2 * val;
    }
  }
  float2 bv = ((const float2*)bias)[lane];
  f32x2 selfv = {bf_lo(sv), bf_hi(sv)};
  float sc = FD ? di : 1.f;                    // self coefficient
  float o0 = fmaxf((acc.x + sc * selfv.x) * di + bv.x, 0.f);
  float o1 = fmaxf((acc.y + sc * selfv.y) * di + bv.y, 0.f);
  ((u32*)hout)[((size_t)node << 6) + lane] = (u32)f2bf(o0) | ((u32)f2bf(o1) << 16);
}

// -- readout: out[M,64] = [h1|h2] @ Wr^T + br (f32 out), 32 rows/block ----
__global__ __launch_bounds__(256) void k_readout(
    const u16* __restrict__ h1, const u16* __restrict__ h2,
    const u16* __restrict__ Wrb, const float* __restrict__ br, float* __restrict__ out){
  int wave = threadIdx.x >> 6, lane = threadIdx.x & 63;
  int m0 = blockIdx.x * 32;
  int n0 = wave * 16;
  int m = lane & 15, q = lane >> 4;
  const u16* a10 = h1 + (size_t)(m0 + m) * HID;
  const u16* a11 = a10 + (size_t)16 * HID;
  const u16* a20 = h2 + (size_t)(m0 + m) * HID;
  const u16* a21 = a20 + (size_t)16 * HID;
  const u16* b  = Wrb + (size_t)(n0 + m) * (2 * HID);
  f32x4 acc0 = {0.f,0.f,0.f,0.f}, acc1 = {0.f,0.f,0.f,0.f};
#pragma unroll
  for (int kb = 0; kb < HID; kb += 32){
    bf16x8 bf = ld8bf(b + kb + q * 8);
    acc0 = __builtin_amdgcn_mfma_f32_16x16x32_bf16(ld8bf(a10 + kb + q * 8), bf, acc0, 0, 0, 0);
    acc1 = __builtin_amdgcn_mfma_f32_16x16x32_bf16(ld8bf(a11 + kb + q * 8), bf, acc1, 0, 0, 0);
  }
#pragma unroll
  for (int kb = 0; kb < HID; kb += 32){
    bf16x8 bf = ld8bf(b + HID + kb + q * 8);
    acc0 = __builtin_amdgcn_mfma_f32_16x16x32_bf16(ld8bf(a20 + kb + q * 8), bf, acc0, 0, 0, 0);
    acc1 = __builtin_amdgcn_mfma_f32_16x16x32_bf16(ld8bf(a21 + kb + q * 8), bf, acc1, 0, 0, 0);
  }
  float bias = br[n0 + m];
  float* crow0 = out + (size_t)(m0 + q * 4) * ODIM + n0 + m;
  float* crow1 = crow0 + (size_t)16 * ODIM;
#pragma unroll
  for (int r = 0; r < 4; r++){
    crow0[(size_t)r * ODIM] = acc0[r] + bias;
    crow1[(size_t)r * ODIM] = acc1[r] + bias;
  }
}

// ---------------- launch --------------------------------------------------
extern "C" void kernel_launch(void* const* d_in, const int* in_sizes, int n_in,
                              void* d_out, int out_size, void* d_ws, size_t ws_size,
                              hipStream_t stream){
  const float* x     = (const float*)d_in[0];
  const int*   eidx  = (const int*)d_in[1];
  const float* eattr = (const float*)d_in[2];
  const float* W1    = (const float*)d_in[3];
  const float* b1    = (const float*)d_in[4];
  const float* W2    = (const float*)d_in[5];
  const float* b2    = (const float*)d_in[6];
  const float* Wr    = (const float*)d_in[7];
  const float* br    = (const float*)d_in[8];
  const int* erow  = eidx;        // edge_index[0]
  const int* ecol  = eidx + NE;   // edge_index[1]

  char* w = (char*)d_ws;
  auto carve = [&](size_t bytes) -> void* {
    void* p = (void*)w;
    w += (bytes + 255) & ~(size_t)255;
    return p;
  };
  u32* csr       = (u32*)carve((size_t)NBK * BINCAP * 4);  // bucket-padded, 4B recs
  u32* bcur      = (u32*)carve(1024);             // bcur+minmax contiguous memset
  u32* minmax    = (u32*)carve(256);
  u32* meta      = (u32*)carve((size_t)NN * 4);   // rs|cnt<<22 packed
  float* dis     = (float*)carve((size_t)NN * 4);
  u16* W2b       = (u16*)carve((size_t)HID * HID * 2);
  u16* Wrb       = (u16*)carve((size_t)ODIM * 2 * HID * 2);
  u16* g         = (u16*)carve((size_t)NN * HID * 2);
  u16* h1        = (u16*)carve((size_t)NN * HID * 2);
  u16* h2        = (u16*)carve((size_t)NN * HID * 2);
  // bin arrays alias h2 (14.5 MB <= 25.6 MB); dead before layer-2 writes h2
  u32* binA      = (u32*)h2;
  u16* binM      = (u16*)((char*)h2 + (size_t)NBK * BINCAP * 4);

  hipMemsetAsync(bcur, 0, 1280, stream);          // bcur + minmax
  // front: bin (critical path, dispatched first) + weight cvt + layer-1 gemm
  k_front<<<BGRID + CVTB + GEMMB, 256, 0, stream>>>(
      eattr, erow, ecol, bcur, binA, binM, minmax,
      x, W1, W2, Wr, W2b, Wrb, g);
  k_scatter<<<NBK, 1024, 0, stream>>>(bcur, binA, binM, minmax, csr, meta, dis);
  // layer 1 aggregate (folds dis[src]*dis[dst] over raw g)
  k_aggregate<true><<<NN / 4, 256, 0, stream>>>(meta, csr, dis, minmax, g, b1, h1);
  // layer 2
  k_gemm128<<<NN / 32, 256, 0, stream>>>(h1, W2b, dis, g);
  k_aggregate<false><<<NN / 4, 256, 0, stream>>>(meta, csr, dis, minmax, g, b2, h2);
  // readout
  k_readout<<<NN / 32, 256, 0, stream>>>(h1, h2, Wrb, br, (float*)d_out);
}

// Round 8
// 374.336 us; speedup vs baseline: 1.5150x; 1.0432x over previous
//
#include <hip/hip_runtime.h>

#define NN 100000
#define NE 1600000
#define HID 128
#define ODIM 64
#define NBK 196          // ceil(NN/512) buckets of 512 nodes
#define BSHIFT 9
#define BINB 200         // bin blocks (1024 thr, 2/CU by LDS)
#define CVTB 8           // weight-cvt blocks (1024 thr)
#define GEMMB 782        // layer-1 gemm blocks (128 rows each)
#define CHUNK 8000       // NE / BINB (exact)
#define BITER 8          // ceil(CHUNK/1024)
#define BINCAP 12288     // records per bucket region (mean ~8800 incl pad)
#define SMAX 8588        // LDS staging records >= 8000 + 196*3
#define LMAX 2148        // line map entries >= SMAX/4

typedef unsigned int u32;
typedef unsigned short u16;
typedef __bf16 bf16x8 __attribute__((ext_vector_type(8)));
typedef float f32x4 __attribute__((ext_vector_type(4)));
typedef float f32x2 __attribute__((ext_vector_type(2)));

__device__ __forceinline__ float bf_lo(u32 p){ return __uint_as_float(p << 16); }
__device__ __forceinline__ float bf_hi(u32 p){ return __uint_as_float(p & 0xffff0000u); }
__device__ __forceinline__ u16 f2bf(float f){
  u32 u = __float_as_uint(f);
  u += 0x7fffu + ((u >> 16) & 1u);   // RTNE
  return (u16)(u >> 16);
}
__device__ __forceinline__ bf16x8 ld8bf(const u16* p){ return *(const bf16x8*)p; }
__device__ __forceinline__ bf16x8 cvt8(const float* p){
  union { bf16x8 v; u16 s[8]; } r;
#pragma unroll
  for (int i = 0; i < 8; i++) r.s[i] = f2bf(p[i]);
  return r.v;
}

// w(mq) = A - B*mq, linear in the 15-bit quantized mean; clip never binds
// (eps in the reference keeps w(mx) = eps/(rng+eps) > 0).
__device__ __forceinline__ void wparams(const u32* minmax, float* A, float* B){
  u32 mnq = 32767u - minmax[0];                // minmax[0] = max(32767-mq)
  u32 mxq = minmax[1];                         // minmax[1] = max(mq)
  u32 rngq = mxq - mnq;
  float inv = rngq ? 1.f / ((float)rngq * (1.f / 32767.f) + 1e-8f) : 0.f;
  *A = 1.f + (float)mnq * (1.f / 32767.f) * inv;
  *B = inv * (1.f / 32767.f);
}

// -- front kernel, 1024-thr blocks:
//    [0,BINB): edge bin, 2-pass low-VGPR (pass1: ecol+count; pass2: recompute)
//    [BINB,+CVTB): weight cvt   [then GEMMB): g_raw = x @ W1^T (no dis)
__global__ __launch_bounds__(1024, 8) void k_front(
    const float* __restrict__ eattr, const int* __restrict__ erow,
    const int* __restrict__ ecol, u32* __restrict__ bcur,
    u32* __restrict__ binA, u16* __restrict__ binM, u32* __restrict__ minmax,
    const float* __restrict__ x, const float* __restrict__ W1,
    const float* __restrict__ W2, const float* __restrict__ Wr,
    u16* __restrict__ W2b, u16* __restrict__ Wrb, u16* __restrict__ graw){
  int tid = threadIdx.x;
  int bid = blockIdx.x;
  if (bid >= BINB + CVTB){                     // ---- layer-1 gemm blocks ----
    int gblk = bid - BINB - CVTB;
    int wv = tid >> 6, lane = tid & 63;
    int mg = wv >> 2, ng = wv & 3;
    int m0 = gblk * 128 + mg * 32;
    int m = lane & 15, q = lane >> 4;
    const float* a0f = x + (size_t)min(m0 + m, NN - 1) * HID;
    const float* a1f = x + (size_t)min(m0 + 16 + m, NN - 1) * HID;
    const float* brow0 = W1 + (size_t)(ng * 16 + m) * HID;   // f32, L2-hot
    const float* brow1 = brow0 + (size_t)64 * HID;
    f32x4 acc00 = {0.f,0.f,0.f,0.f}, acc01 = {0.f,0.f,0.f,0.f};
    f32x4 acc10 = {0.f,0.f,0.f,0.f}, acc11 = {0.f,0.f,0.f,0.f};
#pragma unroll
    for (int kb = 0; kb < HID; kb += 32){
      bf16x8 af0 = cvt8(a0f + kb + q * 8);
      bf16x8 af1 = cvt8(a1f + kb + q * 8);
      bf16x8 bf0 = cvt8(brow0 + kb + q * 8);
      bf16x8 bf1 = cvt8(brow1 + kb + q * 8);
      acc00 = __builtin_amdgcn_mfma_f32_16x16x32_bf16(af0, bf0, acc00, 0, 0, 0);
      acc01 = __builtin_amdgcn_mfma_f32_16x16x32_bf16(af0, bf1, acc01, 0, 0, 0);
      acc10 = __builtin_amdgcn_mfma_f32_16x16x32_bf16(af1, bf0, acc10, 0, 0, 0);
      acc11 = __builtin_amdgcn_mfma_f32_16x16x32_bf16(af1, bf1, acc11, 0, 0, 0);
    }
#pragma unroll
    for (int r = 0; r < 4; r++){
      int row0 = m0 + q * 4 + r, row1 = m0 + 16 + q * 4 + r;
      if (row0 < NN){
        u16* c0 = graw + (size_t)row0 * HID + ng * 16 + m;
        c0[0]  = f2bf(acc00[r]);
        c0[64] = f2bf(acc01[r]);
      }
      if (row1 < NN){
        u16* c1 = graw + (size_t)row1 * HID + ng * 16 + m;
        c1[0]  = f2bf(acc10[r]);
        c1[64] = f2bf(acc11[r]);
      }
    }
    return;
  }
  if (bid >= BINB){                            // ---- weight-cvt blocks ----
    int i = (bid - BINB) * 1024 + tid;         // 8192 float4 slots (W2, Wr)
    const float* src; u16* dst; int off;
    if (i < 4096){ src = W2; dst = W2b; off = i; }
    else { src = Wr; dst = Wrb; off = i - 4096; }
    float4 v = ((const float4*)src)[off];
    uint2 o;
    o.x = (u32)f2bf(v.x) | ((u32)f2bf(v.y) << 16);
    o.y = (u32)f2bf(v.z) | ((u32)f2bf(v.w) << 16);
    ((uint2*)dst)[off] = o;
    return;
  }
  // -------------------------- bin blocks ---------------------------------
  __shared__ u32 lcnt[8 * NBK], wof[8 * NBK];  // per wave-pair group
  __shared__ u32 lofs[NBK], gb[NBK];
  __shared__ u32 wtot[4];
  __shared__ u16 lmap[LMAX];
  __shared__ u32 stageA[SMAX];
  __shared__ u16 stageM[SMAX];
  __shared__ u32 Tt;
  __shared__ u32 sMn[16], sMx[16];
  for (int t = tid; t < 8 * NBK; t += 1024) lcnt[t] = 0;
  __syncthreads();
  int base = bid * CHUNK;
  int wv = tid >> 6, lane = tid & 63;
  int grp = tid >> 7;                          // 8 groups of 2 waves
  // pass 1: ecol only -> per-group bucket counts + packed (b|d|r)
  u32 pk[BITER];
#pragma unroll
  for (int it = 0; it < BITER; it++){
    int idx = it * 1024 + tid;
    u32 p = 0xFFFFFFFFu;
    if (idx < CHUNK){
      int c = ecol[base + idx];
      if ((u32)c < NN){
        u32 b = (u32)c >> BSHIFT;
        u32 r = atomicAdd(&lcnt[grp * NBK + b], 1u);    // r < 1024, fits 13b
        p = (b << 22) | (((u32)c & 511u) << 13) | r;
      }
    }
    pk[it] = p;
  }
  __syncthreads();
  // combine per-group counts -> n, na(pad4); wof = group prefix
  u32 na = 0;
  if (tid < NBK){
    u32 run = 0;
#pragma unroll
    for (int g = 0; g < 8; g++){
      wof[g * NBK + tid] = run;
      run += lcnt[g * NBK + tid];
    }
    na = (run + 3u) & ~3u;
    lofs[tid] = run;                           // stash n temporarily
  }
  // 2-barrier scan over 196 na values (first 4 waves)
  u32 incl = na;
  if (tid < 256){
    for (int off = 1; off < 64; off <<= 1){
      u32 t = (u32)__shfl_up((int)incl, off);
      if (lane >= off) incl += t;
    }
    if (lane == 63) wtot[wv] = incl;
  }
  __syncthreads();
  if (tid < 256){
    u32 pre = 0;
#pragma unroll
    for (int k = 0; k < 4; k++) pre += (k < wv) ? wtot[k] : 0u;
    u32 ex = pre + incl - na;
    if (tid == 255) Tt = pre + incl;
    if (tid < NBK){
      u32 n = lofs[tid];
      lofs[tid] = ex;
      u32 g = 0x80000000u;
      if (na){
        u32 gl = atomicAdd(&bcur[tid], na);    // bcur 0-init by memset
        if (gl + na <= BINCAP) g = (u32)tid * BINCAP + gl;
      }
      gb[tid] = g;
      for (u32 l = ex >> 2; l < (ex + na) >> 2; l++) lmap[l] = (u16)tid;
      for (u32 k = n; k < na; k++){ stageA[ex + k] = 0xFFFFFFFFu; stageM[ex + k] = 0; }
    }
  }
  __syncthreads();
  // pass 2: reload eattr/erow, recompute record, place bucket-major; minmax
  u32 lmn = 0, lmx = 0;                        // lmn holds max(32767-mq)
#pragma unroll
  for (int it = 0; it < BITER; it++){
    int idx = it * 1024 + tid;
    if (idx >= CHUNK) continue;
    int e = base + idx;
    float4 a = ((const float4*)eattr)[e];
    float m = 0.25f * (a.x + a.y + a.z + a.w);
    u32 mq = (u32)(m * 32767.f + 0.5f);        // m in [0,1) -> fits 15 bits
    lmn = max(lmn, 32767u - mq); lmx = max(lmx, mq);
    u32 p = pk[it];
    if (p == 0xFFFFFFFFu) continue;
    u32 s = (u32)erow[e]; if (s >= NN) s = 0;  // never triggers (randint<NN)
    u32 b = p >> 22, d = (p >> 13) & 511u, r = p & 8191u;
    u32 slot = lofs[b] + wof[grp * NBK + b] + r;
    stageA[slot] = s | (d << 17);              // src:17 | d:9
    stageM[slot] = (u16)mq;
  }
  __syncthreads();
  // stream out: consecutive threads -> consecutive slots in 4-record runs
  u32 T = Tt;
  for (u32 i = tid; i < T; i += 1024){
    u32 b = lmap[i >> 2];
    u32 g = gb[b];
    if (g != 0x80000000u){
      u32 o = g + (i - lofs[b]);
      binA[o] = stageA[i];
      binM[o] = stageM[i];
    }
  }
  // integer min/max reduce + global update (0-init compatible encoding)
  for (int off = 32; off; off >>= 1){
    lmn = max(lmn, (u32)__shfl_xor((int)lmn, off));
    lmx = max(lmx, (u32)__shfl_xor((int)lmx, off));
  }
  if (lane == 0){ sMn[wv] = lmn; sMx[wv] = lmx; }
  __syncthreads();
  if (tid == 0){
    u32 mn = 0, mx = 0;
#pragma unroll
    for (int k = 0; k < 16; k++){ mn = max(mn, sMn[k]); mx = max(mx, sMx[k]); }
    atomicMax(&minmax[0], mn);
    atomicMax(&minmax[1], mx);
  }
}

// -- scatter: count+scan+scatter in one kernel, two passes over bucket
//    region (2nd pass L2-hot). 7 KB LDS. Sum(w) is linear in (c, sum mq).
__global__ __launch_bounds__(1024) void k_scatter(
    const u32* __restrict__ bcur, const u32* __restrict__ binA,
    const u16* __restrict__ binM, const u32* __restrict__ minmax,
    u32* __restrict__ csr, u32* __restrict__ meta, float* __restrict__ dis){
  __shared__ u32 cntL[512], sumL[512], curL[512];
  __shared__ u32 wtot[8];
  int b = blockIdx.x, tid = threadIdx.x;
  int bb = b * BINCAP;
  int nrec = (int)min(bcur[b], (u32)BINCAP);
  if (tid < 512){ cntL[tid] = 0; sumL[tid] = 0; }
  __syncthreads();
  for (int i = tid; i < nrec; i += 1024){
    u32 a = binA[bb + i];
    if (a == 0xFFFFFFFFu) continue;            // pad sentinel
    u32 d = (a >> 17) & 511u;
    u32 mq = binM[bb + i];
    atomicAdd(&cntL[d], 1u);
    atomicAdd(&sumL[d], mq);
  }
  __syncthreads();
  float A, B; wparams(minmax, &A, &B);
  int wid = tid >> 6, lane = tid & 63;
  u32 v = 0, incl = 0;
  if (tid < 512){ v = cntL[tid]; incl = v; }
  for (int off = 1; off < 64; off <<= 1){
    u32 t = (u32)__shfl_up((int)incl, off);
    if (lane >= off) incl += t;
  }
  if (tid < 512 && lane == 63) wtot[wid] = incl;
  __syncthreads();
  if (tid < 512){
    u32 pre = 0;
#pragma unroll
    for (int k = 0; k < 8; k++) pre += (k < wid) ? wtot[k] : 0u;
    u32 ex = pre + incl - v;
    curL[tid] = (u32)bb + ex;
    int node = (b << BSHIFT) + tid;
    if (node < NN){
      meta[node] = ((u32)bb + ex) | (v << 22); // rs<2.41M fits 22b; cnt<1024
      float sw = A * (float)v - B * (float)sumL[tid];   // sum of weights
      dis[node] = rsqrtf(1.f + sw);
    }
  }
  __syncthreads();
  for (int i = tid; i < nrec; i += 1024){
    u32 a = binA[bb + i];
    if (a == 0xFFFFFFFFu) continue;
    u32 d = (a >> 17) & 511u;
    u32 mq = binM[bb + i];
    u32 pos = atomicAdd(&curL[d], 1u);         // LDS returning atomic
    csr[pos] = (a & 0x1FFFFu) | (mq << 17);    // src:17 | mq:15
  }
}

// -- bf16 MFMA GEMM (layer 2): G = dis[m]*(A[M,128] @ Bt[128,128]^T) ------
__global__ __launch_bounds__(256) void k_gemm128(
    const u16* __restrict__ Ab, const u16* __restrict__ Bt,
    const float* __restrict__ dis, u16* __restrict__ G){
  int wave = threadIdx.x >> 6, lane = threadIdx.x & 63;
  int m0 = blockIdx.x * 32;
  int m = lane & 15, q = lane >> 4;
  const u16* a0b = Ab + (size_t)(m0 + m) * HID;
  const u16* a1b = a0b + (size_t)16 * HID;
  const u16* brow0 = Bt + (size_t)(wave * 16 + m) * HID;
  const u16* brow1 = brow0 + (size_t)64 * HID;
  f32x4 acc00 = {0.f,0.f,0.f,0.f}, acc01 = {0.f,0.f,0.f,0.f};
  f32x4 acc10 = {0.f,0.f,0.f,0.f}, acc11 = {0.f,0.f,0.f,0.f};
#pragma unroll
  for (int kb = 0; kb < HID; kb += 32){
    bf16x8 af0 = ld8bf(a0b + kb + q * 8);
    bf16x8 af1 = ld8bf(a1b + kb + q * 8);
    bf16x8 bf0 = ld8bf(brow0 + kb + q * 8);
    bf16x8 bf1 = ld8bf(brow1 + kb + q * 8);
    acc00 = __builtin_amdgcn_mfma_f32_16x16x32_bf16(af0, bf0, acc00, 0, 0, 0);
    acc01 = __builtin_amdgcn_mfma_f32_16x16x32_bf16(af0, bf1, acc01, 0, 0, 0);
    acc10 = __builtin_amdgcn_mfma_f32_16x16x32_bf16(af1, bf0, acc10, 0, 0, 0);
    acc11 = __builtin_amdgcn_mfma_f32_16x16x32_bf16(af1, bf1, acc11, 0, 0, 0);
  }
  u16* crow0 = G + (size_t)(m0 + q * 4) * HID + wave * 16 + m;
  u16* crow1 = crow0 + (size_t)16 * HID;
#pragma unroll
  for (int r = 0; r < 4; r++){
    float d0 = dis[m0 + q * 4 + r];
    float d1 = dis[m0 + 16 + q * 4 + r];
    crow0[(size_t)r * HID]      = f2bf(acc00[r] * d0);
    crow0[(size_t)r * HID + 64] = f2bf(acc01[r] * d0);
    crow1[(size_t)r * HID]      = f2bf(acc10[r] * d1);
    crow1[(size_t)r * HID + 64] = f2bf(acc11[r] * d1);
  }
}

// ------- aggregation: wave/node, scalar csr records, w = A - B*mq --------
// FD=false: g has dis folded: h = relu(di*(acc + self) + b)
// FD=true : g is raw x@W1:   h = relu(di*(acc' + di*self) + b),
//           acc' = sum w_e * dis[src] * g_raw[src]  (dis[src] scalar-loaded)
template <bool FD>
__global__ __launch_bounds__(256) void k_aggregate(
    const u32* __restrict__ meta, const u32* __restrict__ csr,
    const float* __restrict__ dis, const u32* __restrict__ minmax,
    const u16* __restrict__ g, const float* __restrict__ bias,
    u16* __restrict__ hout){
  int node = __builtin_amdgcn_readfirstlane(
      (int)(blockIdx.x * 4 + (threadIdx.x >> 6)));
  int lane = threadIdx.x & 63;
  const u32* gp = (const u32*)g;
  u32 sv = gp[((size_t)node << 6) + lane];     // self row, issued early
  u32 mw = meta[node];                          // uniform -> scalar load
  float di = dis[node];                         // uniform -> scalar load
  float A, B; wparams(minmax, &A, &B);
  u32 s = mw & 0x3FFFFFu;
  int c = (int)(mw >> 22);
  const u32* cp = csr + s;
  f32x2 acc = {0.f, 0.f};
  int j = 0;
  // full 16-edge chunks: 16 gathers in flight, no conditionals
  for (; j + 16 <= c; j += 16){
    u32 p[16];
#pragma unroll
    for (int t = 0; t < 16; t++)
      p[t] = __builtin_amdgcn_readfirstlane(cp[j + t]);
    u32 pv[16];
#pragma unroll
    for (int t = 0; t < 16; t++)
      pv[t] = gp[(size_t)(p[t] & 0x1FFFFu) * 64u + lane];
#pragma unroll
    for (int t = 0; t < 16; t++){
      float wf = A - B * (float)(p[t] >> 17);
      if (FD) wf *= dis[p[t] & 0x1FFFFu];      // uniform idx -> scalar load
      f32x2 val = {bf_lo(pv[t]), bf_hi(pv[t])};
      f32x2 w2 = {wf, wf};
      acc += w2 * val;
    }
  }
  // masked 8-edge chunks for the tail (src->0, w->0 beyond c)
  for (; j < c; j += 8){
    u32 p[8];
#pragma unroll
    for (int t = 0; t < 8; t++)
      p[t] = __builtin_amdgcn_readfirstlane(cp[j + t]);  // bucket slack: safe
    u32 st[8]; float wv[8];
#pragma unroll
    for (int t = 0; t < 8; t++){
      bool ok = (j + t) < c;                   // wave-uniform condition
      st[t] = ok ? (p[t] & 0x1FFFFu) : 0u;
      float wf = A - B * (float)(p[t] >> 17);
      if (FD) wf *= dis[st[t]];
      wv[t] = ok ? wf : 0.f;
    }
    u32 pv[8];
#pragma unroll
    for (int t = 0; t < 8; t++)
      pv[t] = gp[(size_t)st[t] * 64u + lane];
#pragma unroll
    for (int t = 0; t < 8; t++){
      f32x2 val = {bf_lo(pv[t]), bf_hi(pv[t])};
      f32x2 w2 = {wv[t], wv[t]};
      acc += w2 * val;
    }
  }
  float2 bv = ((const float2*)bias)[lane];
  f32x2 selfv = {bf_lo(sv), bf_hi(sv)};
  float sc = FD ? di : 1.f;                    // self coefficient
  float o0 = fmaxf((acc.x + sc * selfv.x) * di + bv.x, 0.f);
  float o1 = fmaxf((acc.y + sc * selfv.y) * di + bv.y, 0.f);
  ((u32*)hout)[((size_t)node << 6) + lane] = (u32)f2bf(o0) | ((u32)f2bf(o1) << 16);
}

// -- readout: out[M,64] = [h1|h2] @ Wr^T + br (f32 out), 32 rows/block ----
__global__ __launch_bounds__(256) void k_readout(
    const u16* __restrict__ h1, const u16* __restrict__ h2,
    const u16* __restrict__ Wrb, const float* __restrict__ br, float* __restrict__ out){
  int wave = threadIdx.x >> 6, lane = threadIdx.x & 63;
  int m0 = blockIdx.x * 32;
  int n0 = wave * 16;
  int m = lane & 15, q = lane >> 4;
  const u16* a10 = h1 + (size_t)(m0 + m) * HID;
  const u16* a11 = a10 + (size_t)16 * HID;
  const u16* a20 = h2 + (size_t)(m0 + m) * HID;
  const u16* a21 = a20 + (size_t)16 * HID;
  const u16* b  = Wrb + (size_t)(n0 + m) * (2 * HID);
  f32x4 acc0 = {0.f,0.f,0.f,0.f}, acc1 = {0.f,0.f,0.f,0.f};
#pragma unroll
  for (int kb = 0; kb < HID; kb += 32){
    bf16x8 bf = ld8bf(b + kb + q * 8);
    acc0 = __builtin_amdgcn_mfma_f32_16x16x32_bf16(ld8bf(a10 + kb + q * 8), bf, acc0, 0, 0, 0);
    acc1 = __builtin_amdgcn_mfma_f32_16x16x32_bf16(ld8bf(a11 + kb + q * 8), bf, acc1, 0, 0, 0);
  }
#pragma unroll
  for (int kb = 0; kb < HID; kb += 32){
    bf16x8 bf = ld8bf(b + HID + kb + q * 8);
    acc0 = __builtin_amdgcn_mfma_f32_16x16x32_bf16(ld8bf(a20 + kb + q * 8), bf, acc0, 0, 0, 0);
    acc1 = __builtin_amdgcn_mfma_f32_16x16x32_bf16(ld8bf(a21 + kb + q * 8), bf, acc1, 0, 0, 0);
  }
  float bias = br[n0 + m];
  float* crow0 = out + (size_t)(m0 + q * 4) * ODIM + n0 + m;
  float* crow1 = crow0 + (size_t)16 * ODIM;
#pragma unroll
  for (int r = 0; r < 4; r++){
    crow0[(size_t)r * ODIM] = acc0[r] + bias;
    crow1[(size_t)r * ODIM] = acc1[r] + bias;
  }
}

// ---------------- launch --------------------------------------------------
extern "C" void kernel_launch(void* const* d_in, const int* in_sizes, int n_in,
                              void* d_out, int out_size, void* d_ws, size_t ws_size,
                              hipStream_t stream){
  const float* x     = (const float*)d_in[0];
  const int*   eidx  = (const int*)d_in[1];
  const float* eattr = (const float*)d_in[2];
  const float* W1    = (const float*)d_in[3];
  const float* b1    = (const float*)d_in[4];
  const float* W2    = (const float*)d_in[5];
  const float* b2    = (const float*)d_in[6];
  const float* Wr    = (const float*)d_in[7];
  const float* br    = (const float*)d_in[8];
  const int* erow  = eidx;        // edge_index[0]
  const int* ecol  = eidx + NE;   // edge_index[1]

  char* w = (char*)d_ws;
  auto carve = [&](size_t bytes) -> void* {
    void* p = (void*)w;
    w += (bytes + 255) & ~(size_t)255;
    return p;
  };
  u32* csr       = (u32*)carve((size_t)NBK * BINCAP * 4);  // bucket-padded, 4B recs
  u32* bcur      = (u32*)carve(1024);             // bcur+minmax contiguous memset
  u32* minmax    = (u32*)carve(256);
  u32* meta      = (u32*)carve((size_t)NN * 4);   // rs|cnt<<22 packed
  float* dis     = (float*)carve((size_t)NN * 4);
  u16* W2b       = (u16*)carve((size_t)HID * HID * 2);
  u16* Wrb       = (u16*)carve((size_t)ODIM * 2 * HID * 2);
  u16* g         = (u16*)carve((size_t)NN * HID * 2);
  u16* h1        = (u16*)carve((size_t)NN * HID * 2);
  u16* h2        = (u16*)carve((size_t)NN * HID * 2);
  // bin arrays alias h2 (14.5 MB <= 25.6 MB); dead before layer-2 writes h2
  u32* binA      = (u32*)h2;
  u16* binM      = (u16*)((char*)h2 + (size_t)NBK * BINCAP * 4);

  hipMemsetAsync(bcur, 0, 1280, stream);          // bcur + minmax
  // front: bin (critical path, dispatched first) + weight cvt + layer-1 gemm
  k_front<<<BINB + CVTB + GEMMB, 1024, 0, stream>>>(
      eattr, erow, ecol, bcur, binA, binM, minmax,
      x, W1, W2, Wr, W2b, Wrb, g);
  k_scatter<<<NBK, 1024, 0, stream>>>(bcur, binA, binM, minmax, csr, meta, dis);
  // layer 1 aggregate (folds dis[src]*dis[dst] over raw g)
  k_aggregate<true><<<NN / 4, 256, 0, stream>>>(meta, csr, dis, minmax, g, b1, h1);
  // layer 2
  k_gemm128<<<NN / 32, 256, 0, stream>>>(h1, W2b, dis, g);
  k_aggregate<false><<<NN / 4, 256, 0, stream>>>(meta, csr, dis, minmax, g, b2, h2);
  // readout
  k_readout<<<NN / 32, 256, 0, stream>>>(h1, h2, Wrb, br, (float*)d_out);
}

// Round 9
// 356.306 us; speedup vs baseline: 1.5916x; 1.0506x over previous
//
#include <hip/hip_runtime.h>

#define NN 100000
#define NE 1600000
#define HID 128
#define ODIM 64
#define NBK 196          // ceil(NN/512) buckets of 512 nodes
#define BSHIFT 9
#define BINB 200         // bin blocks (1024 thr, 2/CU by LDS)
#define CVTB 8           // weight-cvt blocks (1024 thr)
#define GEMMB 782        // layer-1 gemm blocks (128 rows each)
#define CHUNK 8000       // NE / BINB (exact)
#define BITER 8          // ceil(CHUNK/1024)
#define BINCAP 12288     // records per bucket region (mean ~8800 incl pad)
#define SMAX 8588        // LDS staging records >= 8000 + 196*3
#define LMAX 2148        // line map entries >= SMAX/4

typedef unsigned int u32;
typedef unsigned short u16;
typedef __bf16 bf16x8 __attribute__((ext_vector_type(8)));
typedef float f32x4 __attribute__((ext_vector_type(4)));
typedef float f32x2 __attribute__((ext_vector_type(2)));

__device__ __forceinline__ float bf_lo(u32 p){ return __uint_as_float(p << 16); }
__device__ __forceinline__ float bf_hi(u32 p){ return __uint_as_float(p & 0xffff0000u); }
__device__ __forceinline__ u16 f2bf(float f){
  u32 u = __float_as_uint(f);
  u += 0x7fffu + ((u >> 16) & 1u);   // RTNE
  return (u16)(u >> 16);
}
__device__ __forceinline__ bf16x8 ld8bf(const u16* p){ return *(const bf16x8*)p; }
__device__ __forceinline__ bf16x8 cvt8(const float* p){
  union { bf16x8 v; u16 s[8]; } r;
#pragma unroll
  for (int i = 0; i < 8; i++) r.s[i] = f2bf(p[i]);
  return r.v;
}

// w(mq) = A - B*mq, linear in the 15-bit quantized mean; clip never binds
// (eps in the reference keeps w(mx) = eps/(rng+eps) > 0).
__device__ __forceinline__ void wparams(const u32* minmax, float* A, float* B){
  u32 mnq = 32767u - minmax[0];                // minmax[0] = max(32767-mq)
  u32 mxq = minmax[1];                         // minmax[1] = max(mq)
  u32 rngq = mxq - mnq;
  float inv = rngq ? 1.f / ((float)rngq * (1.f / 32767.f) + 1e-8f) : 0.f;
  *A = 1.f + (float)mnq * (1.f / 32767.f) * inv;
  *B = inv * (1.f / 32767.f);
}

// -- front kernel, 1024-thr blocks:
//    [0,BINB): edge bin, 2-pass low-VGPR (pass1: ecol+count; pass2: recompute)
//    [BINB,+CVTB): weight cvt   [then GEMMB): g_raw = x @ W1^T (no dis)
__global__ __launch_bounds__(1024, 8) void k_front(
    const float* __restrict__ eattr, const int* __restrict__ erow,
    const int* __restrict__ ecol, u32* __restrict__ bcur,
    uint2* __restrict__ bin8, u32* __restrict__ minmax,
    const float* __restrict__ x, const float* __restrict__ W1,
    const float* __restrict__ W2, const float* __restrict__ Wr,
    u16* __restrict__ W2b, u16* __restrict__ Wrb, u16* __restrict__ graw){
  int tid = threadIdx.x;
  int bid = blockIdx.x;
  if (bid >= BINB + CVTB){                     // ---- layer-1 gemm blocks ----
    int gblk = bid - BINB - CVTB;
    int wv = tid >> 6, lane = tid & 63;
    int mg = wv >> 2, ng = wv & 3;
    int m0 = gblk * 128 + mg * 32;
    int m = lane & 15, q = lane >> 4;
    const float* a0f = x + (size_t)min(m0 + m, NN - 1) * HID;
    const float* a1f = x + (size_t)min(m0 + 16 + m, NN - 1) * HID;
    const float* brow0 = W1 + (size_t)(ng * 16 + m) * HID;   // f32, L2-hot
    const float* brow1 = brow0 + (size_t)64 * HID;
    f32x4 acc00 = {0.f,0.f,0.f,0.f}, acc01 = {0.f,0.f,0.f,0.f};
    f32x4 acc10 = {0.f,0.f,0.f,0.f}, acc11 = {0.f,0.f,0.f,0.f};
#pragma unroll
    for (int kb = 0; kb < HID; kb += 32){
      bf16x8 af0 = cvt8(a0f + kb + q * 8);
      bf16x8 af1 = cvt8(a1f + kb + q * 8);
      bf16x8 bf0 = cvt8(brow0 + kb + q * 8);
      bf16x8 bf1 = cvt8(brow1 + kb + q * 8);
      acc00 = __builtin_amdgcn_mfma_f32_16x16x32_bf16(af0, bf0, acc00, 0, 0, 0);
      acc01 = __builtin_amdgcn_mfma_f32_16x16x32_bf16(af0, bf1, acc01, 0, 0, 0);
      acc10 = __builtin_amdgcn_mfma_f32_16x16x32_bf16(af1, bf0, acc10, 0, 0, 0);
      acc11 = __builtin_amdgcn_mfma_f32_16x16x32_bf16(af1, bf1, acc11, 0, 0, 0);
    }
#pragma unroll
    for (int r = 0; r < 4; r++){
      int row0 = m0 + q * 4 + r, row1 = m0 + 16 + q * 4 + r;
      if (row0 < NN){
        u16* c0 = graw + (size_t)row0 * HID + ng * 16 + m;
        c0[0]  = f2bf(acc00[r]);
        c0[64] = f2bf(acc01[r]);
      }
      if (row1 < NN){
        u16* c1 = graw + (size_t)row1 * HID + ng * 16 + m;
        c1[0]  = f2bf(acc10[r]);
        c1[64] = f2bf(acc11[r]);
      }
    }
    return;
  }
  if (bid >= BINB){                            // ---- weight-cvt blocks ----
    int i = (bid - BINB) * 1024 + tid;         // 8192 float4 slots (W2, Wr)
    const float* src; u16* dst; int off;
    if (i < 4096){ src = W2; dst = W2b; off = i; }
    else { src = Wr; dst = Wrb; off = i - 4096; }
    float4 v = ((const float4*)src)[off];
    uint2 o;
    o.x = (u32)f2bf(v.x) | ((u32)f2bf(v.y) << 16);
    o.y = (u32)f2bf(v.z) | ((u32)f2bf(v.w) << 16);
    ((uint2*)dst)[off] = o;
    return;
  }
  // -------------------------- bin blocks ---------------------------------
  __shared__ u32 lcnt[8 * NBK], wof[8 * NBK];  // per wave-pair group
  __shared__ u32 lofs[NBK], gb[NBK];
  __shared__ u32 wtot[4];
  __shared__ u16 lmap[LMAX];
  __shared__ u32 stageA[SMAX];
  __shared__ u16 stageM[SMAX];
  __shared__ u32 Tt;
  __shared__ u32 sMn[16], sMx[16];
  for (int t = tid; t < 8 * NBK; t += 1024) lcnt[t] = 0;
  __syncthreads();
  int base = bid * CHUNK;
  int wv = tid >> 6, lane = tid & 63;
  int grp = tid >> 7;                          // 8 groups of 2 waves
  // pass 1: ecol only -> per-group bucket counts + packed (b|d|r)
  u32 pk[BITER];
#pragma unroll
  for (int it = 0; it < BITER; it++){
    int idx = it * 1024 + tid;
    u32 p = 0xFFFFFFFFu;
    if (idx < CHUNK){
      int c = ecol[base + idx];
      if ((u32)c < NN){
        u32 b = (u32)c >> BSHIFT;
        u32 r = atomicAdd(&lcnt[grp * NBK + b], 1u);    // r < 1024, fits 13b
        p = (b << 22) | (((u32)c & 511u) << 13) | r;
      }
    }
    pk[it] = p;
  }
  __syncthreads();
  // combine per-group counts -> n, na(pad4); wof = group prefix
  u32 na = 0;
  if (tid < NBK){
    u32 run = 0;
#pragma unroll
    for (int g = 0; g < 8; g++){
      wof[g * NBK + tid] = run;
      run += lcnt[g * NBK + tid];
    }
    na = (run + 3u) & ~3u;
    lofs[tid] = run;                           // stash n temporarily
  }
  // 2-barrier scan over 196 na values (first 4 waves)
  u32 incl = na;
  if (tid < 256){
    for (int off = 1; off < 64; off <<= 1){
      u32 t = (u32)__shfl_up((int)incl, off);
      if (lane >= off) incl += t;
    }
    if (lane == 63) wtot[wv] = incl;
  }
  __syncthreads();
  if (tid < 256){
    u32 pre = 0;
#pragma unroll
    for (int k = 0; k < 4; k++) pre += (k < wv) ? wtot[k] : 0u;
    u32 ex = pre + incl - na;
    if (tid == 255) Tt = pre + incl;
    if (tid < NBK){
      u32 n = lofs[tid];
      lofs[tid] = ex;
      u32 g = 0x80000000u;
      if (na){
        u32 gl = atomicAdd(&bcur[tid], na);    // bcur 0-init by memset
        if (gl + na <= BINCAP) g = (u32)tid * BINCAP + gl;
      }
      gb[tid] = g;
      for (u32 l = ex >> 2; l < (ex + na) >> 2; l++) lmap[l] = (u16)tid;
      for (u32 k = n; k < na; k++){ stageA[ex + k] = 0xFFFFFFFFu; stageM[ex + k] = 0; }
    }
  }
  __syncthreads();
  // pass 2: reload eattr/erow, recompute record, place bucket-major; minmax
  u32 lmn = 0, lmx = 0;                        // lmn holds max(32767-mq)
#pragma unroll
  for (int it = 0; it < BITER; it++){
    int idx = it * 1024 + tid;
    if (idx >= CHUNK) continue;
    int e = base + idx;
    float4 a = ((const float4*)eattr)[e];
    float m = 0.25f * (a.x + a.y + a.z + a.w);
    u32 mq = (u32)(m * 32767.f + 0.5f);        // m in [0,1) -> fits 15 bits
    lmn = max(lmn, 32767u - mq); lmx = max(lmx, mq);
    u32 p = pk[it];
    if (p == 0xFFFFFFFFu) continue;
    u32 s = (u32)erow[e]; if (s >= NN) s = 0;  // never triggers (randint<NN)
    u32 b = p >> 22, d = (p >> 13) & 511u, r = p & 8191u;
    u32 slot = lofs[b] + wof[grp * NBK + b] + r;
    stageA[slot] = s | (d << 17);              // src:17 | d:9
    stageM[slot] = (u16)mq;
  }
  __syncthreads();
  // stream out: 8B records, consecutive threads -> consecutive slots
  u32 T = Tt;
  for (u32 i = tid; i < T; i += 1024){
    u32 b = lmap[i >> 2];
    u32 g = gb[b];
    if (g != 0x80000000u){
      uint2 rec; rec.x = stageA[i]; rec.y = (u32)stageM[i];
      bin8[g + (i - lofs[b])] = rec;
    }
  }
  // integer min/max reduce + global update (0-init compatible encoding)
  for (int off = 32; off; off >>= 1){
    lmn = max(lmn, (u32)__shfl_xor((int)lmn, off));
    lmx = max(lmx, (u32)__shfl_xor((int)lmx, off));
  }
  if (lane == 0){ sMn[wv] = lmn; sMx[wv] = lmx; }
  __syncthreads();
  if (tid == 0){
    u32 mn = 0, mx = 0;
#pragma unroll
    for (int k = 0; k < 16; k++){ mn = max(mn, sMn[k]); mx = max(mx, sMx[k]); }
    atomicMax(&minmax[0], mn);
    atomicMax(&minmax[1], mx);
  }
}

// -- scatter: count+scan+scatter, two passes over bucket region (2nd L2-hot)
//    8B records (one load each); 4-way privatized counters (less contention).
__global__ __launch_bounds__(1024) void k_scatter(
    const u32* __restrict__ bcur, const uint2* __restrict__ bin8,
    const u32* __restrict__ minmax, u32* __restrict__ csr,
    u32* __restrict__ meta, float* __restrict__ dis){
  __shared__ u32 cnt4[4 * 512], sum4[4 * 512];
  __shared__ u32 curL[512];
  __shared__ u32 wtot[8];
  int b = blockIdx.x, tid = threadIdx.x;
  int grp = tid >> 8;                          // 4 groups of 4 waves
  int bb = b * BINCAP;
  int nrec = (int)min(bcur[b], (u32)BINCAP);
  for (int t = tid; t < 4 * 512; t += 1024){ cnt4[t] = 0; sum4[t] = 0; }
  __syncthreads();
  for (int i = tid; i < nrec; i += 1024){
    uint2 r = bin8[bb + i];
    if (r.x == 0xFFFFFFFFu) continue;          // pad sentinel
    u32 d = (r.x >> 17) & 511u;
    atomicAdd(&cnt4[grp * 512 + d], 1u);
    atomicAdd(&sum4[grp * 512 + d], r.y);
  }
  __syncthreads();
  float A, B; wparams(minmax, &A, &B);
  int wid = tid >> 6, lane = tid & 63;
  u32 v = 0, sm = 0, incl = 0;
  if (tid < 512){
    v  = cnt4[tid] + cnt4[512 + tid] + cnt4[1024 + tid] + cnt4[1536 + tid];
    sm = sum4[tid] + sum4[512 + tid] + sum4[1024 + tid] + sum4[1536 + tid];
    incl = v;
  }
  for (int off = 1; off < 64; off <<= 1){
    u32 t = (u32)__shfl_up((int)incl, off);
    if (lane >= off) incl += t;
  }
  if (tid < 512 && lane == 63) wtot[wid] = incl;
  __syncthreads();
  if (tid < 512){
    u32 pre = 0;
#pragma unroll
    for (int k = 0; k < 8; k++) pre += (k < wid) ? wtot[k] : 0u;
    u32 ex = pre + incl - v;
    curL[tid] = (u32)bb + ex;
    int node = (b << BSHIFT) + tid;
    if (node < NN){
      meta[node] = ((u32)bb + ex) | (v << 22); // rs<2.41M fits 22b; cnt<1024
      float sw = A * (float)v - B * (float)sm; // sum of weights
      dis[node] = rsqrtf(1.f + sw);
    }
  }
  __syncthreads();
  for (int i = tid; i < nrec; i += 1024){
    uint2 r = bin8[bb + i];
    if (r.x == 0xFFFFFFFFu) continue;
    u32 d = (r.x >> 17) & 511u;
    u32 pos = atomicAdd(&curL[d], 1u);         // LDS returning atomic
    csr[pos] = (r.x & 0x1FFFFu) | (r.y << 17); // src:17 | mq:15
  }
}

// -- bf16 MFMA GEMM (layer 2): G = dis[m]*(A[M,128] @ Bt[128,128]^T) ------
__global__ __launch_bounds__(256) void k_gemm128(
    const u16* __restrict__ Ab, const u16* __restrict__ Bt,
    const float* __restrict__ dis, u16* __restrict__ G){
  int wave = threadIdx.x >> 6, lane = threadIdx.x & 63;
  int m0 = blockIdx.x * 32;
  int m = lane & 15, q = lane >> 4;
  const u16* a0b = Ab + (size_t)(m0 + m) * HID;
  const u16* a1b = a0b + (size_t)16 * HID;
  const u16* brow0 = Bt + (size_t)(wave * 16 + m) * HID;
  const u16* brow1 = brow0 + (size_t)64 * HID;
  f32x4 acc00 = {0.f,0.f,0.f,0.f}, acc01 = {0.f,0.f,0.f,0.f};
  f32x4 acc10 = {0.f,0.f,0.f,0.f}, acc11 = {0.f,0.f,0.f,0.f};
#pragma unroll
  for (int kb = 0; kb < HID; kb += 32){
    bf16x8 af0 = ld8bf(a0b + kb + q * 8);
    bf16x8 af1 = ld8bf(a1b + kb + q * 8);
    bf16x8 bf0 = ld8bf(brow0 + kb + q * 8);
    bf16x8 bf1 = ld8bf(brow1 + kb + q * 8);
    acc00 = __builtin_amdgcn_mfma_f32_16x16x32_bf16(af0, bf0, acc00, 0, 0, 0);
    acc01 = __builtin_amdgcn_mfma_f32_16x16x32_bf16(af0, bf1, acc01, 0, 0, 0);
    acc10 = __builtin_amdgcn_mfma_f32_16x16x32_bf16(af1, bf0, acc10, 0, 0, 0);
    acc11 = __builtin_amdgcn_mfma_f32_16x16x32_bf16(af1, bf1, acc11, 0, 0, 0);
  }
  u16* crow0 = G + (size_t)(m0 + q * 4) * HID + wave * 16 + m;
  u16* crow1 = crow0 + (size_t)16 * HID;
#pragma unroll
  for (int r = 0; r < 4; r++){
    float d0 = dis[m0 + q * 4 + r];
    float d1 = dis[m0 + 16 + q * 4 + r];
    crow0[(size_t)r * HID]      = f2bf(acc00[r] * d0);
    crow0[(size_t)r * HID + 64] = f2bf(acc01[r] * d0);
    crow1[(size_t)r * HID]      = f2bf(acc10[r] * d1);
    crow1[(size_t)r * HID + 64] = f2bf(acc11[r] * d1);
  }
}

// ------- aggregation layer 1: wave/node, scalar csr records --------------
// g is raw x@W1: h = relu(di*(acc' + di*self) + b), acc' = sum w*dis[src]*g
__global__ __launch_bounds__(256) void k_aggregate(
    const u32* __restrict__ meta, const u32* __restrict__ csr,
    const float* __restrict__ dis, const u32* __restrict__ minmax,
    const u16* __restrict__ g, const float* __restrict__ bias,
    u16* __restrict__ hout){
  int node = __builtin_amdgcn_readfirstlane(
      (int)(blockIdx.x * 4 + (threadIdx.x >> 6)));
  int lane = threadIdx.x & 63;
  const u32* gp = (const u32*)g;
  u32 sv = gp[((size_t)node << 6) + lane];     // self row, issued early
  u32 mw = meta[node];                          // uniform -> scalar load
  float di = dis[node];                         // uniform -> scalar load
  float A, B; wparams(minmax, &A, &B);
  u32 s = mw & 0x3FFFFFu;
  int c = (int)(mw >> 22);
  const u32* cp = csr + s;
  f32x2 acc = {0.f, 0.f};
  int j = 0;
  for (; j + 16 <= c; j += 16){
    u32 p[16];
#pragma unroll
    for (int t = 0; t < 16; t++)
      p[t] = __builtin_amdgcn_readfirstlane(cp[j + t]);
    u32 pv[16];
#pragma unroll
    for (int t = 0; t < 16; t++)
      pv[t] = gp[(size_t)(p[t] & 0x1FFFFu) * 64u + lane];
#pragma unroll
    for (int t = 0; t < 16; t++){
      float wf = (A - B * (float)(p[t] >> 17)) * dis[p[t] & 0x1FFFFu];
      f32x2 val = {bf_lo(pv[t]), bf_hi(pv[t])};
      f32x2 w2 = {wf, wf};
      acc += w2 * val;
    }
  }
  for (; j < c; j += 8){
    u32 p[8];
#pragma unroll
    for (int t = 0; t < 8; t++)
      p[t] = __builtin_amdgcn_readfirstlane(cp[j + t]);  // bucket slack: safe
    u32 st[8]; float wv[8];
#pragma unroll
    for (int t = 0; t < 8; t++){
      bool ok = (j + t) < c;                   // wave-uniform condition
      st[t] = ok ? (p[t] & 0x1FFFFu) : 0u;
      wv[t] = ok ? (A - B * (float)(p[t] >> 17)) * dis[st[t]] : 0.f;
    }
    u32 pv[8];
#pragma unroll
    for (int t = 0; t < 8; t++)
      pv[t] = gp[(size_t)st[t] * 64u + lane];
#pragma unroll
    for (int t = 0; t < 8; t++){
      f32x2 val = {bf_lo(pv[t]), bf_hi(pv[t])};
      f32x2 w2 = {wv[t], wv[t]};
      acc += w2 * val;
    }
  }
  float2 bv = ((const float2*)bias)[lane];
  f32x2 selfv = {bf_lo(sv), bf_hi(sv)};
  float o0 = fmaxf((acc.x + di * selfv.x) * di + bv.x, 0.f);
  float o1 = fmaxf((acc.y + di * selfv.y) * di + bv.y, 0.f);
  ((u32*)hout)[((size_t)node << 6) + lane] = (u32)f2bf(o0) | ((u32)f2bf(o1) << 16);
}

// ------- aggregation layer 2 + fused readout -----------------------------
// 16 waves/block, one node each; h2 never hits HBM. After aggregation the
// hcat tile [16][256] is staged in LDS, then waves 0-3 run the 16x64 MFMA
// readout tile (identical fragment addressing to the proven k_readout).
__global__ __launch_bounds__(1024) void k_agg_read(
    const u32* __restrict__ meta, const u32* __restrict__ csr,
    const float* __restrict__ dis, const u32* __restrict__ minmax,
    const u16* __restrict__ g, const float* __restrict__ bias,
    const u16* __restrict__ h1, const u16* __restrict__ Wrb,
    const float* __restrict__ br, float* __restrict__ out){
  __shared__ u16 hc[16][264];                  // hcat tile, +8 pad per row
  int wv = threadIdx.x >> 6, lane = threadIdx.x & 63;
  int node0 = blockIdx.x * 16;
  int node = __builtin_amdgcn_readfirstlane(node0 + wv);
  const u32* gp = (const u32*)g;
  u32 sv = gp[((size_t)node << 6) + lane];     // self row (dis-folded g)
  u32 mw = meta[node];
  float di = dis[node];
  float A, B; wparams(minmax, &A, &B);
  u32 s = mw & 0x3FFFFFu;
  int c = (int)(mw >> 22);
  const u32* cp = csr + s;
  f32x2 acc = {0.f, 0.f};
  int j = 0;
  for (; j + 16 <= c; j += 16){
    u32 p[16];
#pragma unroll
    for (int t = 0; t < 16; t++)
      p[t] = __builtin_amdgcn_readfirstlane(cp[j + t]);
    u32 pv[16];
#pragma unroll
    for (int t = 0; t < 16; t++)
      pv[t] = gp[(size_t)(p[t] & 0x1FFFFu) * 64u + lane];
#pragma unroll
    for (int t = 0; t < 16; t++){
      float wf = A - B * (float)(p[t] >> 17);
      f32x2 val = {bf_lo(pv[t]), bf_hi(pv[t])};
      f32x2 w2 = {wf, wf};
      acc += w2 * val;
    }
  }
  for (; j < c; j += 8){
    u32 p[8];
#pragma unroll
    for (int t = 0; t < 8; t++)
      p[t] = __builtin_amdgcn_readfirstlane(cp[j + t]);  // bucket slack: safe
    u32 st[8]; float wvv[8];
#pragma unroll
    for (int t = 0; t < 8; t++){
      bool ok = (j + t) < c;
      st[t] = ok ? (p[t] & 0x1FFFFu) : 0u;
      wvv[t] = ok ? (A - B * (float)(p[t] >> 17)) : 0.f;
    }
    u32 pv[8];
#pragma unroll
    for (int t = 0; t < 8; t++)
      pv[t] = gp[(size_t)st[t] * 64u + lane];
#pragma unroll
    for (int t = 0; t < 8; t++){
      f32x2 val = {bf_lo(pv[t]), bf_hi(pv[t])};
      f32x2 w2 = {wvv[t], wvv[t]};
      acc += w2 * val;
    }
  }
  float2 bv = ((const float2*)bias)[lane];
  f32x2 selfv = {bf_lo(sv), bf_hi(sv)};
  float o0 = fmaxf((acc.x + selfv.x) * di + bv.x, 0.f);
  float o1 = fmaxf((acc.y + selfv.y) * di + bv.y, 0.f);
  // stage hcat: h1 row (loaded) | h2 row (just computed, same rounding as before)
  u32 h2pk = (u32)f2bf(o0) | ((u32)f2bf(o1) << 16);
  *(u32*)&hc[wv][2 * lane] = ((const u32*)h1)[((size_t)node << 6) + lane];
  *(u32*)&hc[wv][128 + 2 * lane] = h2pk;
  __syncthreads();
  // readout: waves 0-3 compute out[node0..+16][wv*16..+16]
  if (wv < 4){
    int m = lane & 15, q = lane >> 4;
    const u16* b = Wrb + (size_t)(wv * 16 + m) * (2 * HID);
    f32x4 acc4 = {0.f,0.f,0.f,0.f};
#pragma unroll
    for (int kb = 0; kb < 2 * HID; kb += 32){
      bf16x8 af = *(const bf16x8*)&hc[m][kb + q * 8];
      bf16x8 bf = ld8bf(b + kb + q * 8);
      acc4 = __builtin_amdgcn_mfma_f32_16x16x32_bf16(af, bf, acc4, 0, 0, 0);
    }
    float bb = br[wv * 16 + m];
#pragma unroll
    for (int r = 0; r < 4; r++)
      out[(size_t)(node0 + q * 4 + r) * ODIM + wv * 16 + m] = acc4[r] + bb;
  }
}

// ---------------- launch --------------------------------------------------
extern "C" void kernel_launch(void* const* d_in, const int* in_sizes, int n_in,
                              void* d_out, int out_size, void* d_ws, size_t ws_size,
                              hipStream_t stream){
  const float* x     = (const float*)d_in[0];
  const int*   eidx  = (const int*)d_in[1];
  const float* eattr = (const float*)d_in[2];
  const float* W1    = (const float*)d_in[3];
  const float* b1    = (const float*)d_in[4];
  const float* W2    = (const float*)d_in[5];
  const float* b2    = (const float*)d_in[6];
  const float* Wr    = (const float*)d_in[7];
  const float* br    = (const float*)d_in[8];
  const int* erow  = eidx;        // edge_index[0]
  const int* ecol  = eidx + NE;   // edge_index[1]

  char* w = (char*)d_ws;
  auto carve = [&](size_t bytes) -> void* {
    void* p = (void*)w;
    w += (bytes + 255) & ~(size_t)255;
    return p;
  };
  u32* csr       = (u32*)carve((size_t)NBK * BINCAP * 4);  // bucket-padded, 4B recs
  u32* bcur      = (u32*)carve(1024);             // bcur+minmax contiguous memset
  u32* minmax    = (u32*)carve(256);
  u32* meta      = (u32*)carve((size_t)NN * 4);   // rs|cnt<<22 packed
  float* dis     = (float*)carve((size_t)NN * 4);
  u16* W2b       = (u16*)carve((size_t)HID * HID * 2);
  u16* Wrb       = (u16*)carve((size_t)ODIM * 2 * HID * 2);
  u16* g         = (u16*)carve((size_t)NN * HID * 2);
  u16* h1        = (u16*)carve((size_t)NN * HID * 2);
  uint2* bin8    = (uint2*)carve((size_t)NBK * BINCAP * 8);  // 8B records

  hipMemsetAsync(bcur, 0, 1280, stream);          // bcur + minmax
  // front: bin (critical path, dispatched first) + weight cvt + layer-1 gemm
  k_front<<<BINB + CVTB + GEMMB, 1024, 0, stream>>>(
      eattr, erow, ecol, bcur, bin8, minmax,
      x, W1, W2, Wr, W2b, Wrb, g);
  k_scatter<<<NBK, 1024, 0, stream>>>(bcur, bin8, minmax, csr, meta, dis);
  // layer 1 aggregate (folds dis[src]*dis[dst] over raw g)
  k_aggregate<<<NN / 4, 256, 0, stream>>>(meta, csr, dis, minmax, g, b1, h1);
  // layer 2 gemm (dis folded into g)
  k_gemm128<<<NN / 32, 256, 0, stream>>>(h1, W2b, dis, g);
  // layer 2 aggregate + fused readout (h2 never hits HBM)
  k_agg_read<<<NN / 16, 1024, 0, stream>>>(meta, csr, dis, minmax, g, b2,
                                           h1, Wrb, br, (float*)d_out);
}